// Round 2
// baseline (1350.059 us; speedup 1.0000x reference)
//
#include <hip/hip_runtime.h>
#include <stdint.h>

#define T_TOK 8192
#define D_DIM 1024
#define H_DIM 4096
#define NGU   8192          // 2*H interleaved gate/up columns
#define NEXP  8
#define MAX_YT 72           // sum ceil(cnt_e/256) <= 2*8192/256 + 8

typedef float  f32x4  __attribute__((ext_vector_type(4)));
typedef __bf16 bf16x8 __attribute__((ext_vector_type(8)));
typedef __bf16 bf16x4 __attribute__((ext_vector_type(4)));

__device__ __forceinline__ void gl_lds16(const void* g, void* l) {
  // async global->LDS, 16B/lane; LDS dest = wave-uniform base + lane*16
  __builtin_amdgcn_global_load_lds(
      (__attribute__((address_space(1))) void*)g,
      (__attribute__((address_space(3))) void*)l, 16u, 0, 0u);
}

// compile-time fence + runtime barrier: sched_barrier(0) keeps the compiler
// from hoisting ds_reads above the cross-wave vmcnt landing guarantee.
#define SFENCE() __builtin_amdgcn_sched_barrier(0)
#define BARRIER() do { SFENCE(); __builtin_amdgcn_s_barrier(); SFENCE(); } while (0)
#define VM0 asm volatile("s_waitcnt vmcnt(0)" ::: "memory")
#define VM4 asm volatile("s_waitcnt vmcnt(4)" ::: "memory")
#define VM6 asm volatile("s_waitcnt vmcnt(6)" ::: "memory")
#define VM8 asm volatile("s_waitcnt vmcnt(8)" ::: "memory")
#define VM_NONE ((void)0)

// ---------------- router (+ fused x->bf16 cast) -----------------------------
__global__ __launch_bounds__(256) void router_kernel(
    const float* __restrict__ x, const float* __restrict__ rw,
    const float* __restrict__ temp, __bf16* __restrict__ xb,
    int* __restrict__ rowtok, float* __restrict__ rowwt,
    int* __restrict__ cnt, float* __restrict__ imp_part,
    float* __restrict__ ent_part)
{
  const int wid  = threadIdx.x >> 6;
  const int lane = threadIdx.x & 63;
  const int t    = blockIdx.x * 4 + wid;   // one wave per token

  float acc[8];
#pragma unroll
  for (int e = 0; e < 8; e++) acc[e] = 0.f;
  const float* xr = x + (size_t)t * D_DIM;
#pragma unroll
  for (int it = 0; it < 4; it++) {
    int d = (it * 64 + lane) * 4;
    float4 v = *(const float4*)(xr + d);
    bf16x4 o;
    o[0] = (__bf16)v.x; o[1] = (__bf16)v.y;
    o[2] = (__bf16)v.z; o[3] = (__bf16)v.w;
    *(bf16x4*)(xb + (size_t)t * D_DIM + d) = o;
    float vv[4] = {v.x, v.y, v.z, v.w};
#pragma unroll
    for (int j = 0; j < 4; j++) {
      float xv = vv[j];
      const float4 r0 = *(const float4*)(rw + (d + j) * 8);
      const float4 r1 = *(const float4*)(rw + (d + j) * 8 + 4);
      acc[0] += xv * r0.x; acc[1] += xv * r0.y;
      acc[2] += xv * r0.z; acc[3] += xv * r0.w;
      acc[4] += xv * r1.x; acc[5] += xv * r1.y;
      acc[6] += xv * r1.z; acc[7] += xv * r1.w;
    }
  }
#pragma unroll
  for (int e = 0; e < 8; e++) {
    float v = acc[e];
#pragma unroll
    for (int off = 32; off > 0; off >>= 1) v += __shfl_xor(v, off, 64);
    acc[e] = v;     // all lanes now hold the full logit
  }
  float tclamp = fminf(fmaxf(temp[0], 0.1f), 5.0f);
  float invt = 1.0f / tclamp;
  float mx = -1e30f;
#pragma unroll
  for (int e = 0; e < 8; e++) { acc[e] *= invt; mx = fmaxf(mx, acc[e]); }
  float p[8]; float s = 0.f;
#pragma unroll
  for (int e = 0; e < 8; e++) { p[e] = __expf(acc[e] - mx); s += p[e]; }
  float invs = 1.0f / s;
  float ent = 0.f;
#pragma unroll
  for (int e = 0; e < 8; e++) {
    p[e] *= invs;
    ent -= p[e] * __logf(fmaxf(p[e], 1e-8f));
  }
  // top-2, ties -> lowest index (matches jax top_k)
  int i1 = 0; float w1 = p[0];
#pragma unroll
  for (int e = 1; e < 8; e++) if (p[e] > w1) { w1 = p[e]; i1 = e; }
  int i2 = (i1 == 0) ? 1 : 0; float w2 = p[i2];
#pragma unroll
  for (int e = 0; e < 8; e++) if (e != i1 && p[e] > w2) { w2 = p[e]; i2 = e; }

  __shared__ float s_imp[4][8];
  __shared__ float s_ent[4];
  if (lane == 0) {
    int pos1 = atomicAdd(&cnt[i1], 1);
    rowtok[i1 * T_TOK + pos1] = t * 2;        // hid row index = t*2 + slot
    rowwt [i1 * T_TOK + pos1] = w1;
    int pos2 = atomicAdd(&cnt[i2], 1);
    rowtok[i2 * T_TOK + pos2] = t * 2 + 1;
    rowwt [i2 * T_TOK + pos2] = w2;
#pragma unroll
    for (int e = 0; e < 8; e++) s_imp[wid][e] = p[e];
    s_ent[wid] = ent;
  }
  __syncthreads();
  if (threadIdx.x < 8) {
    int e = threadIdx.x;
    imp_part[blockIdx.x * 8 + e] =
        s_imp[0][e] + s_imp[1][e] + s_imp[2][e] + s_imp[3][e];
  } else if (threadIdx.x == 8) {
    ent_part[blockIdx.x] = s_ent[0] + s_ent[1] + s_ent[2] + s_ent[3];
  }
}

// ---------------- aux losses + GEMM tile schedule (256-row M tiles) ---------
__global__ __launch_bounds__(256) void aux_final_kernel(
    const float* __restrict__ imp_part, const float* __restrict__ ent_part,
    const int* __restrict__ cnt, int* __restrict__ tileoff,
    float* __restrict__ out_aux)
{
  __shared__ float simp[256];
  __shared__ float sent[256];
  int tid = threadIdx.x;
  int e = tid & 7, g = tid >> 3;
  float ia = 0.f;
  for (int b = g; b < 2048; b += 32) ia += imp_part[b * 8 + e];
  simp[tid] = ia;
  float ea = 0.f;
  for (int b = tid; b < 2048; b += 256) ea += ent_part[b];
  sent[tid] = ea;
  __syncthreads();
  if (tid == 0) {
    float imp[8] = {0,0,0,0,0,0,0,0};
    float ent = 0.f;
    for (int i = 0; i < 256; i++) { imp[i & 7] += simp[i]; ent += sent[i]; }
    float aux = 0.f;
    for (int ee = 0; ee < 8; ee++) {
      float importance = imp[ee] / 8192.0f;
      float load = (float)cnt[ee] / (8192.0f + 1e-6f);
      aux += importance * load;
    }
    out_aux[0] = aux * 8.0f * 0.01f;
    out_aux[1] = (ent / 8192.0f) * 0.01f;
    out_aux[2] = 0.f;
    int off = 0;
    for (int ee = 0; ee < 8; ee++) { tileoff[ee] = off; off += (cnt[ee] + 255) >> 8; }
    tileoff[8] = off;
  }
}

// ---------------- fused vectorized transpose+cast of all weights ------------
__global__ __launch_bounds__(256) void transpose_all_kernel(
    const float* __restrict__ Wg, const float* __restrict__ Wu,
    const float* __restrict__ Wd,
    __bf16* __restrict__ BguT, __bf16* __restrict__ BdT)
{
  __shared__ float tile[64 * 129];
  int z = blockIdx.z;
  const float* src; __bf16* dst;
  int C, Kd, r0, c0, up = 0;
  bool gu = z < 16;
  if (gu) {
    int e = z >> 1; up = z & 1;
    src = (up ? Wu : Wg) + (size_t)e * D_DIM * H_DIM;
    dst = BguT + (size_t)e * NGU * D_DIM;
    C = H_DIM; Kd = D_DIM;
    c0 = (blockIdx.x & 31) << 7;  r0 = (blockIdx.x >> 5) << 6;
  } else {
    int e = z - 16;
    src = Wd + (size_t)e * H_DIM * D_DIM;
    dst = BdT + (size_t)e * D_DIM * H_DIM;
    C = D_DIM; Kd = H_DIM;
    c0 = (blockIdx.x & 7) << 7;   r0 = (blockIdx.x >> 3) << 6;
  }
  int t = threadIdx.x;
  int cq = t & 31, rb = t >> 5;
#pragma unroll
  for (int i = 0; i < 8; i++) {
    int r = rb + 8 * i;
    float4 v = *(const float4*)(src + (size_t)(r0 + r) * C + c0 + cq * 4);
    *(float4*)&tile[r * 129 + cq * 4] = v;
  }
  __syncthreads();
#pragma unroll
  for (int i = 0; i < 4; i++) {
    int c = t + (i << 8);         // chunk id 0..1023
    int hl = c >> 3;              // dst-row local (src-col local) 0..127
    int rc = c & 7;               // 8-elem k-chunk within dst row
    int dstrow;
    if (gu) { int h = c0 + hl; dstrow = ((h >> 4) << 5) + (h & 15) + (up << 4); }
    else    { dstrow = c0 + hl; }
    bf16x8 o;
#pragma unroll
    for (int j = 0; j < 8; j++)
      o[j] = (__bf16)tile[(rc * 8 + j) * 129 + hl];
    *(bf16x8*)(dst + (size_t)dstrow * Kd + r0 + rc * 8) = o;
  }
}

// ---------------- 256x256 8-phase GEMM machinery ----------------------------
// LDS tile layout (per buffer): row-major [256 rows][64 K], XOR-swizzled:
// LDS chunk c of row r holds global k-chunk (c ^ (r&7)); read with the same
// XOR -> ds_read_b128 conflict-free.
//
// Stage units (16 KB = 2 gl_lds16/thread), death-region-matched to the
// quadrant phase sequence p1:(qm0,qn0) p2:(0,1) p3:(1,0) p4:(1,1):
//   A0 = A rows {0-63,128-191}   (read p1,p2)   A1 = {64-127,192-255} (p3,p4)
//   B0 = B rows {0-31,64-95,128-159,192-223} (p1,p3)  B1 = +32 strips (p2,p4)
// Issue stream (tile t):  p1: A1(t+1)  p2: B1(t+1)  p3: A0(t+2)  p4: B0(t+2)
// Steady state at t.p1 start: outstanding = [A1(t),B1(t),A0(t+1),B0(t+1)].
// vmcnt(6)@p1-end lands A1(t),B1(t); vmcnt(8)@p4-end lands A0(t+1),B0(t+1).
// TAIL: at t=NT-2 the t+2 stages are skipped, so p4's vmcnt(8) is a no-op and
// the last tile's A0/B0 have no landing guarantee -> peel the last tile with
// an explicit vmcnt(4)+barrier pre-drain and vmcnt(0) after its first MFMAs.

#define STAGE_A0(tt, NTT) do { if ((tt) < (NTT)) {                             \
    int b_ = (tt) & 1; int k_ = (tt) << 6;                                     \
    gl_lds16(aptr[0] + k_, &As[b_][aoff]);                                     \
    gl_lds16(aptr[2] + k_, &As[b_][aoff + 2 * 4096]); } } while (0)
#define STAGE_A1(tt, NTT) do { if ((tt) < (NTT)) {                             \
    int b_ = (tt) & 1; int k_ = (tt) << 6;                                     \
    gl_lds16(aptr[1] + k_, &As[b_][aoff + 1 * 4096]);                          \
    gl_lds16(aptr[3] + k_, &As[b_][aoff + 3 * 4096]); } } while (0)
#define STAGE_B0(tt, NTT) do { if ((tt) < (NTT)) {                             \
    int b_ = (tt) & 1; int k_ = (tt) << 6;                                     \
    gl_lds16(bptr[0] + k_, &Bs[b_][boff0]);                                    \
    gl_lds16(bptr[2] + k_, &Bs[b_][boff2]); } } while (0)
#define STAGE_B1(tt, NTT) do { if ((tt) < (NTT)) {                             \
    int b_ = (tt) & 1; int k_ = (tt) << 6;                                     \
    gl_lds16(bptr[1] + k_, &Bs[b_][boff1]);                                    \
    gl_lds16(bptr[3] + k_, &Bs[b_][boff3]); } } while (0)

#define PHASE(QM, QN, STAGE_STMT, WAIT_STMT) do {                              \
  bf16x8 af_[4][2], bf_[2][2];                                                 \
  _Pragma("unroll")                                                            \
  for (int mi_ = 0; mi_ < 4; mi_++) {                                          \
    int r_ = wm * 128 + (QM) * 64 + mi_ * 16 + l15;                            \
    _Pragma("unroll")                                                          \
    for (int kk_ = 0; kk_ < 2; kk_++) {                                        \
      int kx_ = (kk_ * 4 + l4) ^ (r_ & 7);                                     \
      af_[mi_][kk_] = *(const bf16x8*)&Ac[(r_ * 8 + kx_) * 8];                 \
    }                                                                          \
  }                                                                            \
  _Pragma("unroll")                                                            \
  for (int ni_ = 0; ni_ < 2; ni_++) {                                          \
    int r_ = wn * 64 + (QN) * 32 + ni_ * 16 + l15;                             \
    _Pragma("unroll")                                                          \
    for (int kk_ = 0; kk_ < 2; kk_++) {                                        \
      int kx_ = (kk_ * 4 + l4) ^ (r_ & 7);                                     \
      bf_[ni_][kk_] = *(const bf16x8*)&Bc[(r_ * 8 + kx_) * 8];                 \
    }                                                                          \
  }                                                                            \
  STAGE_STMT;                                                                  \
  BARRIER();                                                                   \
  __builtin_amdgcn_s_setprio(1);                                               \
  _Pragma("unroll")                                                            \
  for (int kk_ = 0; kk_ < 2; kk_++)                                            \
    _Pragma("unroll")                                                          \
    for (int mi_ = 0; mi_ < 4; mi_++)                                          \
      _Pragma("unroll")                                                        \
      for (int ni_ = 0; ni_ < 2; ni_++)                                        \
        acc[(QM) * 4 + mi_][(QN) * 2 + ni_] =                                  \
            __builtin_amdgcn_mfma_f32_16x16x32_bf16(                           \
                af_[mi_][kk_], bf_[ni_][kk_],                                  \
                acc[(QM) * 4 + mi_][(QN) * 2 + ni_], 0, 0, 0);                 \
  __builtin_amdgcn_s_setprio(0);                                               \
  WAIT_STMT;                                                                   \
  BARRIER();                                                                   \
} while (0)

// ---------------- GEMM1: gathered x @ BguT[e], fused SwiGLU, scaled by we ---
__global__ __launch_bounds__(512, 2) void gemm1_kernel(
    const __bf16* __restrict__ xb, const __bf16* __restrict__ BguT,
    const int* __restrict__ rowtok, const float* __restrict__ rowwt,
    const int* __restrict__ cnt, const int* __restrict__ tileoff,
    __bf16* __restrict__ hid)
{
  __shared__ __bf16 As[2][256 * 64];
  __shared__ __bf16 Bs[2][256 * 64];
  __shared__ int   s_tok[256];
  __shared__ float s_wt[256];

  int y = blockIdx.y;
  if (y >= tileoff[8]) return;
  int e = 0;
  while (y >= tileoff[e + 1]) e++;
  int m0 = (y - tileoff[e]) << 8;
  int cntE = cnt[e];
  int tid = threadIdx.x;
  if (tid < 256) {
    int m = m0 + tid;
    bool v = m < cntE;
    s_tok[tid] = v ? rowtok[e * T_TOK + m] : 0;
    s_wt [tid] = v ? rowwt [e * T_TOK + m] : 0.f;
  }
  __syncthreads();

  const int n0 = blockIdx.x << 8;
  const __bf16* Bp = BguT + (size_t)e * NGU * D_DIM;
  const int lane = tid & 63;
  const int wid  = tid >> 6;
  const int wm = wid >> 2, wn = wid & 3;     // 2(M) x 4(N) waves, 128x64 each
  const int l15 = lane & 15, l4 = lane >> 4;

  // per-thread staging geometry: rr = LDS row-in-call, ch = k-chunk
  const int rr = tid >> 3, ch = tid & 7;
  const int swz = (ch ^ (rr & 7)) << 3;       // row&7 == rr&7 for all calls
  const int rB = rr + ((rr >> 5) << 5);       // rr<32 ? rr : rr+32
  const int aoff = rr * 64 + ch * 8;          // quarter-0 LDS elem offset

  const __bf16* aptr[4];
#pragma unroll
  for (int Q = 0; Q < 4; Q++)
    aptr[Q] = xb + (size_t)(s_tok[Q * 64 + rr] >> 1) * D_DIM + swz;
  const __bf16* bptr[4];
  const int bb0 = 0, bb1 = 32, bb2 = 128, bb3 = 160;
  bptr[0] = Bp + (size_t)(n0 + bb0 + rB) * D_DIM + swz;
  bptr[1] = Bp + (size_t)(n0 + bb1 + rB) * D_DIM + swz;
  bptr[2] = Bp + (size_t)(n0 + bb2 + rB) * D_DIM + swz;
  bptr[3] = Bp + (size_t)(n0 + bb3 + rB) * D_DIM + swz;
  const int boff0 = (bb0 + rB) * 64 + ch * 8;
  const int boff1 = (bb1 + rB) * 64 + ch * 8;
  const int boff2 = (bb2 + rB) * 64 + ch * 8;
  const int boff3 = (bb3 + rB) * 64 + ch * 8;

  f32x4 acc[8][4];
#pragma unroll
  for (int a = 0; a < 8; a++)
#pragma unroll
    for (int b = 0; b < 4; b++) acc[a][b] = (f32x4){0.f, 0.f, 0.f, 0.f};

  // prologue: tile0 full + tile1 A0,B0; vmcnt(8) -> tile0 A0,B0 landed
  STAGE_A0(0, 16); STAGE_B0(0, 16); STAGE_A1(0, 16); STAGE_B1(0, 16);
  STAGE_A0(1, 16); STAGE_B0(1, 16);
  VM8;
  BARRIER();

  for (int t = 0; t < 15; t++) {
    const __bf16* Ac = &As[t & 1][0];
    const __bf16* Bc = &Bs[t & 1][0];
    PHASE(0, 0, STAGE_A1(t + 1, 16), VM6);
    PHASE(0, 1, STAGE_B1(t + 1, 16), VM_NONE);
    PHASE(1, 0, STAGE_A0(t + 2, 16), VM_NONE);
    PHASE(1, 1, STAGE_B0(t + 2, 16), VM8);
  }
  // peeled last tile (t=15, buffer 1): pre-drain A0/B0, then drain A1/B1
  VM4;
  BARRIER();
  {
    const __bf16* Ac = &As[1][0];
    const __bf16* Bc = &Bs[1][0];
    PHASE(0, 0, VM_NONE, VM0);
    PHASE(0, 1, VM_NONE, VM_NONE);
    PHASE(1, 0, VM_NONE, VM_NONE);
    PHASE(1, 1, VM_NONE, VM_NONE);
  }

  // SwiGLU epilogue: n-tile pair (even=gate, odd=up) is lane-aligned
#pragma unroll
  for (int mi = 0; mi < 8; mi++) {
#pragma unroll
    for (int p2 = 0; p2 < 2; p2++) {
      f32x4 gt = acc[mi][2 * p2];
      f32x4 up = acc[mi][2 * p2 + 1];
      int nb = n0 + wn * 64 + p2 * 32;
      int h = ((nb >> 5) << 4) + l15;
#pragma unroll
      for (int r = 0; r < 4; r++) {
        int rl = wm * 128 + mi * 16 + l4 * 4 + r;
        if (m0 + rl < cntE) {
          float u = up[r];
          float hv = (u / (1.f + __expf(-u))) * gt[r] * s_wt[rl];
          hid[(size_t)s_tok[rl] * H_DIM + h] = (__bf16)hv;
        }
      }
    }
  }
}

// ---------------- GEMM2: hid @ BdT[e], K-split x2, store ytmp[z][2T][D] -----
__global__ __launch_bounds__(512, 2) void gemm2_kernel(
    const __bf16* __restrict__ hid, const __bf16* __restrict__ BdT,
    const int* __restrict__ rowtok, const int* __restrict__ cnt,
    const int* __restrict__ tileoff, float* __restrict__ ytmp)
{
  __shared__ __bf16 As[2][256 * 64];
  __shared__ __bf16 Bs[2][256 * 64];
  __shared__ int s_tok[256];

  int y = blockIdx.y;
  if (y >= tileoff[8]) return;
  int e = 0;
  while (y >= tileoff[e + 1]) e++;
  int m0 = (y - tileoff[e]) << 8;
  int cntE = cnt[e];
  int tid = threadIdx.x;
  if (tid < 256) {
    int m = m0 + tid;
    s_tok[tid] = (m < cntE) ? rowtok[e * T_TOK + m] : 0;
  }
  __syncthreads();

  const int n0 = blockIdx.x << 8;            // 4 n-blocks over D=1024
  const int kz = blockIdx.z << 11;           // K-half offset (0 / 2048)
  const __bf16* Bp = BdT + (size_t)e * D_DIM * H_DIM;
  const int lane = tid & 63;
  const int wid  = tid >> 6;
  const int wm = wid >> 2, wn = wid & 3;
  const int l15 = lane & 15, l4 = lane >> 4;

  const int rr = tid >> 3, ch = tid & 7;
  const int swz = (ch ^ (rr & 7)) << 3;
  const int rB = rr + ((rr >> 5) << 5);
  const int aoff = rr * 64 + ch * 8;

  const __bf16* aptr[4];
#pragma unroll
  for (int Q = 0; Q < 4; Q++)
    aptr[Q] = hid + (size_t)s_tok[Q * 64 + rr] * H_DIM + kz + swz;
  const __bf16* bptr[4];
  const int bb0 = 0, bb1 = 32, bb2 = 128, bb3 = 160;
  bptr[0] = Bp + (size_t)(n0 + bb0 + rB) * H_DIM + kz + swz;
  bptr[1] = Bp + (size_t)(n0 + bb1 + rB) * H_DIM + kz + swz;
  bptr[2] = Bp + (size_t)(n0 + bb2 + rB) * H_DIM + kz + swz;
  bptr[3] = Bp + (size_t)(n0 + bb3 + rB) * H_DIM + kz + swz;
  const int boff0 = (bb0 + rB) * 64 + ch * 8;
  const int boff1 = (bb1 + rB) * 64 + ch * 8;
  const int boff2 = (bb2 + rB) * 64 + ch * 8;
  const int boff3 = (bb3 + rB) * 64 + ch * 8;

  f32x4 acc[8][4];
#pragma unroll
  for (int a = 0; a < 8; a++)
#pragma unroll
    for (int b = 0; b < 4; b++) acc[a][b] = (f32x4){0.f, 0.f, 0.f, 0.f};

  STAGE_A0(0, 32); STAGE_B0(0, 32); STAGE_A1(0, 32); STAGE_B1(0, 32);
  STAGE_A0(1, 32); STAGE_B0(1, 32);
  VM8;
  BARRIER();

  for (int t = 0; t < 31; t++) {
    const __bf16* Ac = &As[t & 1][0];
    const __bf16* Bc = &Bs[t & 1][0];
    PHASE(0, 0, STAGE_A1(t + 1, 32), VM6);
    PHASE(0, 1, STAGE_B1(t + 1, 32), VM_NONE);
    PHASE(1, 0, STAGE_A0(t + 2, 32), VM_NONE);
    PHASE(1, 1, STAGE_B0(t + 2, 32), VM8);
  }
  // peeled last tile (t=31, buffer 1)
  VM4;
  BARRIER();
  {
    const __bf16* Ac = &As[1][0];
    const __bf16* Bc = &Bs[1][0];
    PHASE(0, 0, VM_NONE, VM0);
    PHASE(0, 1, VM_NONE, VM_NONE);
    PHASE(1, 0, VM_NONE, VM_NONE);
    PHASE(1, 1, VM_NONE, VM_NONE);
  }

  float* yz = ytmp + (size_t)blockIdx.z * (2 * T_TOK) * D_DIM;
#pragma unroll
  for (int mi = 0; mi < 8; mi++)
#pragma unroll
    for (int nj = 0; nj < 4; nj++) {
      int coln = n0 + wn * 64 + nj * 16 + l15;
#pragma unroll
      for (int r = 0; r < 4; r++) {
        int rl = wm * 128 + mi * 16 + l4 * 4 + r;
        if (m0 + rl < cntE)
          yz[(size_t)s_tok[rl] * D_DIM + coln] = acc[mi][nj][r];
      }
    }
}

// ---------------- combine: out[t] = sum of 2 slots x 2 K-halves -------------
__global__ __launch_bounds__(256) void combine_kernel(
    const float* __restrict__ ytmp, float* __restrict__ out)
{
  size_t i = ((size_t)blockIdx.x * 256 + threadIdx.x) * 4;
  size_t t = i >> 10;            // D=1024
  size_t col = i & 1023;
  const size_t HZ = (size_t)(2 * T_TOK) * D_DIM;
  const float4 a = *(const float4*)(ytmp + ((t * 2) << 10) + col);
  const float4 b = *(const float4*)(ytmp + ((t * 2 + 1) << 10) + col);
  const float4 c = *(const float4*)(ytmp + HZ + ((t * 2) << 10) + col);
  const float4 d = *(const float4*)(ytmp + HZ + ((t * 2 + 1) << 10) + col);
  float4 o = {a.x + b.x + c.x + d.x, a.y + b.y + c.y + d.y,
              a.z + b.z + c.z + d.z, a.w + b.w + c.w + d.w};
  *(float4*)(out + i) = o;
}

// ---------------- launch ----------------------------------------------------
extern "C" void kernel_launch(void* const* d_in, const int* in_sizes, int n_in,
                              void* d_out, int out_size, void* d_ws, size_t ws_size,
                              hipStream_t stream)
{
  const float* x    = (const float*)d_in[0];
  const float* rw   = (const float*)d_in[1];
  const float* temp = (const float*)d_in[2];
  const float* Wg   = (const float*)d_in[3];
  const float* Wu   = (const float*)d_in[4];
  const float* Wd   = (const float*)d_in[5];
  float* out = (float*)d_out;

  char* ws = (char*)d_ws;
  size_t off = 0;
  auto alloc = [&](size_t bytes) -> void* {
    void* p = ws + off;
    off = (off + bytes + 255) & ~(size_t)255;
    return p;
  };
  __bf16* xb     = (__bf16*)alloc((size_t)T_TOK * D_DIM * 2);
  __bf16* BguT   = (__bf16*)alloc((size_t)NEXP * NGU * D_DIM * 2);
  __bf16* BdT    = (__bf16*)alloc((size_t)NEXP * D_DIM * H_DIM * 2);
  __bf16* hid    = (__bf16*)alloc((size_t)T_TOK * 2 * H_DIM * 2);
  int*    rowtok = (int*)  alloc((size_t)NEXP * T_TOK * 4);
  float*  rowwt  = (float*)alloc((size_t)NEXP * T_TOK * 4);
  int*    cnt    = (int*)  alloc(64);
  int*    tileoff= (int*)  alloc(64);
  float*  imp_part = (float*)alloc(2048 * 8 * 4);
  float*  ent_part = (float*)alloc(2048 * 4);
  // ytmp (2 K-halves x 2T x D fp32 = 128 MiB) aliases BguT (128 MiB): BguT is
  // dead after gemm1; gemm2 (stream-ordered) writes ytmp, combine reads it.
  float* ytmp = (float*)BguT;
  (void)ws_size; (void)n_in; (void)in_sizes;

  hipMemsetAsync(cnt, 0, 64, stream);

  router_kernel<<<2048, 256, 0, stream>>>(x, rw, temp, xb, rowtok, rowwt, cnt,
                                          imp_part, ent_part);
  aux_final_kernel<<<1, 256, 0, stream>>>(imp_part, ent_part, cnt, tileoff,
                                          out + (size_t)T_TOK * D_DIM);
  transpose_all_kernel<<<dim3(512, 1, 24), 256, 0, stream>>>(Wg, Wu, Wd,
                                                             BguT, BdT);
  gemm1_kernel<<<dim3(32, MAX_YT), 512, 0, stream>>>(xb, BguT, rowtok, rowwt,
                                                     cnt, tileoff, hid);
  gemm2_kernel<<<dim3(4, MAX_YT, 2), 512, 0, stream>>>(hid, BdT, rowtok, cnt,
                                                       tileoff, ytmp);
  combine_kernel<<<8192, 256, 0, stream>>>(ytmp, out);
}

// Round 3
// 1237.674 us; speedup vs baseline: 1.0908x; 1.0908x over previous
//
#include <hip/hip_runtime.h>
#include <stdint.h>

#define T_TOK 8192
#define D_DIM 1024
#define H_DIM 4096
#define NGU   8192          // 2*H interleaved gate/up columns
#define NEXP  8
#define MAX_YT 72           // sum ceil(cnt_e/256) <= 2*8192/256 + 8

typedef float  f32x4  __attribute__((ext_vector_type(4)));
typedef __bf16 bf16x8 __attribute__((ext_vector_type(8)));
typedef __bf16 bf16x4 __attribute__((ext_vector_type(4)));

__device__ __forceinline__ void gl_lds16(const void* g, void* l) {
  // async global->LDS, 16B/lane; LDS dest = wave-uniform base + lane*16
  __builtin_amdgcn_global_load_lds(
      (__attribute__((address_space(1))) void*)g,
      (__attribute__((address_space(3))) void*)l, 16u, 0, 0u);
}

// compile-time fence + runtime barrier: sched_barrier(0) keeps the compiler
// from hoisting ds_reads above the cross-wave vmcnt landing guarantee.
#define SFENCE() __builtin_amdgcn_sched_barrier(0)
#define BARRIER() do { SFENCE(); __builtin_amdgcn_s_barrier(); SFENCE(); } while (0)
#define VM0 asm volatile("s_waitcnt vmcnt(0)" ::: "memory")
#define VM4 asm volatile("s_waitcnt vmcnt(4)" ::: "memory")
#define VM6 asm volatile("s_waitcnt vmcnt(6)" ::: "memory")
#define VM8 asm volatile("s_waitcnt vmcnt(8)" ::: "memory")
#define VM_NONE ((void)0)

// ---------------- router (+ fused x->bf16 cast) -----------------------------
__global__ __launch_bounds__(256) void router_kernel(
    const float* __restrict__ x, const float* __restrict__ rw,
    const float* __restrict__ temp, __bf16* __restrict__ xb,
    int* __restrict__ rowtok, float* __restrict__ rowwt,
    int* __restrict__ cnt, float* __restrict__ imp_part,
    float* __restrict__ ent_part)
{
  const int wid  = threadIdx.x >> 6;
  const int lane = threadIdx.x & 63;
  const int t    = blockIdx.x * 4 + wid;   // one wave per token

  float acc[8];
#pragma unroll
  for (int e = 0; e < 8; e++) acc[e] = 0.f;
  const float* xr = x + (size_t)t * D_DIM;
#pragma unroll
  for (int it = 0; it < 4; it++) {
    int d = (it * 64 + lane) * 4;
    float4 v = *(const float4*)(xr + d);
    bf16x4 o;
    o[0] = (__bf16)v.x; o[1] = (__bf16)v.y;
    o[2] = (__bf16)v.z; o[3] = (__bf16)v.w;
    *(bf16x4*)(xb + (size_t)t * D_DIM + d) = o;
    float vv[4] = {v.x, v.y, v.z, v.w};
#pragma unroll
    for (int j = 0; j < 4; j++) {
      float xv = vv[j];
      const float4 r0 = *(const float4*)(rw + (d + j) * 8);
      const float4 r1 = *(const float4*)(rw + (d + j) * 8 + 4);
      acc[0] += xv * r0.x; acc[1] += xv * r0.y;
      acc[2] += xv * r0.z; acc[3] += xv * r0.w;
      acc[4] += xv * r1.x; acc[5] += xv * r1.y;
      acc[6] += xv * r1.z; acc[7] += xv * r1.w;
    }
  }
#pragma unroll
  for (int e = 0; e < 8; e++) {
    float v = acc[e];
#pragma unroll
    for (int off = 32; off > 0; off >>= 1) v += __shfl_xor(v, off, 64);
    acc[e] = v;     // all lanes now hold the full logit
  }
  float tclamp = fminf(fmaxf(temp[0], 0.1f), 5.0f);
  float invt = 1.0f / tclamp;
  float mx = -1e30f;
#pragma unroll
  for (int e = 0; e < 8; e++) { acc[e] *= invt; mx = fmaxf(mx, acc[e]); }
  float p[8]; float s = 0.f;
#pragma unroll
  for (int e = 0; e < 8; e++) { p[e] = __expf(acc[e] - mx); s += p[e]; }
  float invs = 1.0f / s;
  float ent = 0.f;
#pragma unroll
  for (int e = 0; e < 8; e++) {
    p[e] *= invs;
    ent -= p[e] * __logf(fmaxf(p[e], 1e-8f));
  }
  // top-2, ties -> lowest index (matches jax top_k)
  int i1 = 0; float w1 = p[0];
#pragma unroll
  for (int e = 1; e < 8; e++) if (p[e] > w1) { w1 = p[e]; i1 = e; }
  int i2 = (i1 == 0) ? 1 : 0; float w2 = p[i2];
#pragma unroll
  for (int e = 0; e < 8; e++) if (e != i1 && p[e] > w2) { w2 = p[e]; i2 = e; }

  __shared__ float s_imp[4][8];
  __shared__ float s_ent[4];
  if (lane == 0) {
    int pos1 = atomicAdd(&cnt[i1], 1);
    rowtok[i1 * T_TOK + pos1] = t * 2;        // hid row index = t*2 + slot
    rowwt [i1 * T_TOK + pos1] = w1;
    int pos2 = atomicAdd(&cnt[i2], 1);
    rowtok[i2 * T_TOK + pos2] = t * 2 + 1;
    rowwt [i2 * T_TOK + pos2] = w2;
#pragma unroll
    for (int e = 0; e < 8; e++) s_imp[wid][e] = p[e];
    s_ent[wid] = ent;
  }
  __syncthreads();
  if (threadIdx.x < 8) {
    int e = threadIdx.x;
    imp_part[blockIdx.x * 8 + e] =
        s_imp[0][e] + s_imp[1][e] + s_imp[2][e] + s_imp[3][e];
  } else if (threadIdx.x == 8) {
    ent_part[blockIdx.x] = s_ent[0] + s_ent[1] + s_ent[2] + s_ent[3];
  }
}

// ---------------- aux losses + GEMM tile schedule (256-row M tiles) ---------
__global__ __launch_bounds__(256) void aux_final_kernel(
    const float* __restrict__ imp_part, const float* __restrict__ ent_part,
    const int* __restrict__ cnt, int* __restrict__ tileoff,
    float* __restrict__ out_aux)
{
  __shared__ float simp[256];
  __shared__ float sent[256];
  int tid = threadIdx.x;
  int e = tid & 7, g = tid >> 3;
  float ia = 0.f;
  for (int b = g; b < 2048; b += 32) ia += imp_part[b * 8 + e];
  simp[tid] = ia;
  float ea = 0.f;
  for (int b = tid; b < 2048; b += 256) ea += ent_part[b];
  sent[tid] = ea;
  __syncthreads();
  if (tid == 0) {
    float imp[8] = {0,0,0,0,0,0,0,0};
    float ent = 0.f;
    for (int i = 0; i < 256; i++) { imp[i & 7] += simp[i]; ent += sent[i]; }
    float aux = 0.f;
    for (int ee = 0; ee < 8; ee++) {
      float importance = imp[ee] / 8192.0f;
      float load = (float)cnt[ee] / (8192.0f + 1e-6f);
      aux += importance * load;
    }
    out_aux[0] = aux * 8.0f * 0.01f;
    out_aux[1] = (ent / 8192.0f) * 0.01f;
    out_aux[2] = 0.f;
    int off = 0;
    for (int ee = 0; ee < 8; ee++) { tileoff[ee] = off; off += (cnt[ee] + 255) >> 8; }
    tileoff[8] = off;
  }
}

// ---------------- fused vectorized transpose+cast of all weights ------------
__global__ __launch_bounds__(256) void transpose_all_kernel(
    const float* __restrict__ Wg, const float* __restrict__ Wu,
    const float* __restrict__ Wd,
    __bf16* __restrict__ BguT, __bf16* __restrict__ BdT)
{
  __shared__ float tile[64 * 129];
  int z = blockIdx.z;
  const float* src; __bf16* dst;
  int C, Kd, r0, c0, up = 0;
  bool gu = z < 16;
  if (gu) {
    int e = z >> 1; up = z & 1;
    src = (up ? Wu : Wg) + (size_t)e * D_DIM * H_DIM;
    dst = BguT + (size_t)e * NGU * D_DIM;
    C = H_DIM; Kd = D_DIM;
    c0 = (blockIdx.x & 31) << 7;  r0 = (blockIdx.x >> 5) << 6;
  } else {
    int e = z - 16;
    src = Wd + (size_t)e * H_DIM * D_DIM;
    dst = BdT + (size_t)e * D_DIM * H_DIM;
    C = D_DIM; Kd = H_DIM;
    c0 = (blockIdx.x & 7) << 7;   r0 = (blockIdx.x >> 3) << 6;
  }
  int t = threadIdx.x;
  int cq = t & 31, rb = t >> 5;
#pragma unroll
  for (int i = 0; i < 8; i++) {
    int r = rb + 8 * i;
    float4 v = *(const float4*)(src + (size_t)(r0 + r) * C + c0 + cq * 4);
    *(float4*)&tile[r * 129 + cq * 4] = v;
  }
  __syncthreads();
#pragma unroll
  for (int i = 0; i < 4; i++) {
    int c = t + (i << 8);         // chunk id 0..1023
    int hl = c >> 3;              // dst-row local (src-col local) 0..127
    int rc = c & 7;               // 8-elem k-chunk within dst row
    int dstrow;
    if (gu) { int h = c0 + hl; dstrow = ((h >> 4) << 5) + (h & 15) + (up << 4); }
    else    { dstrow = c0 + hl; }
    bf16x8 o;
#pragma unroll
    for (int j = 0; j < 8; j++)
      o[j] = (__bf16)tile[(rc * 8 + j) * 129 + hl];
    *(bf16x8*)(dst + (size_t)dstrow * Kd + r0 + rc * 8) = o;
  }
}

// ---------------- 256x256 8-phase GEMM machinery ----------------------------
// LDS tile layout (per buffer): row-major [256 rows][64 K], XOR-swizzled:
// LDS chunk c of row r holds global k-chunk (c ^ (r&7)); read with the same
// XOR -> ds_read_b128 conflict-free.
//
// Fragment-resident phase order (0,0)->(0,1)->(1,1)->(1,0): 24 ds_read_b128
// per wave per K-tile (minimal; was 48 with per-phase re-reads -> LDS pipe
// was the critical path, MfmaUtil capped at ~28%).
//   p1: LOADA(0) 8 + LOADB0 4 reads     p2: LOADB1 4 reads (af held)
//   p3: LOADA(1) 8 reads (bf1 held)     p4: 0 reads (bf0 held since p1)
//
// Stage units (16 KB = 2 gl_lds16/thread), death-region-matched:
//   A0 = A rows {0-63,128-191} (QM=0, read p1)  A1 = {64-127,192-255} (p3)
//   B0 = B rows {0-31,64-95,128-159,192-223} (QN=0, read p1)  B1 = +32 (p2)
// Issue stream (tile t): p1: A1(t+1)  p2: B1(t+1)  p3: A0(t+2)  p4: B0(t+2)
// WAR: A0(t+2) written p3, last read p1 (2+ barriers);  B0(t+2) written p4,
// last read p1.  A1/B1(t+1) write the other buffer.  All safe.
// Landing: VM8@t.p4 forces A0/B0(t+1) before t+1.p1 reads; VM6@t.p1 forces
// A1/B1(t) before t.p2/p3 reads.  TAIL: last tile's A0/B0 stages are guard-
// skipped so VM8 under-counts -> peel last tile with VM4+barrier pre-drain
// and VM0 after its p1 MFMAs (lands A1/B1 for p2/p3).

#define STAGE_A0(tt, NTT) do { if ((tt) < (NTT)) {                             \
    int b_ = (tt) & 1; int k_ = (tt) << 6;                                     \
    gl_lds16(aptr[0] + k_, &As[b_][aoff]);                                     \
    gl_lds16(aptr[2] + k_, &As[b_][aoff + 2 * 4096]); } } while (0)
#define STAGE_A1(tt, NTT) do { if ((tt) < (NTT)) {                             \
    int b_ = (tt) & 1; int k_ = (tt) << 6;                                     \
    gl_lds16(aptr[1] + k_, &As[b_][aoff + 1 * 4096]);                          \
    gl_lds16(aptr[3] + k_, &As[b_][aoff + 3 * 4096]); } } while (0)
#define STAGE_B0(tt, NTT) do { if ((tt) < (NTT)) {                             \
    int b_ = (tt) & 1; int k_ = (tt) << 6;                                     \
    gl_lds16(bptr[0] + k_, &Bs[b_][boff0]);                                    \
    gl_lds16(bptr[2] + k_, &Bs[b_][boff2]); } } while (0)
#define STAGE_B1(tt, NTT) do { if ((tt) < (NTT)) {                             \
    int b_ = (tt) & 1; int k_ = (tt) << 6;                                     \
    gl_lds16(bptr[1] + k_, &Bs[b_][boff1]);                                    \
    gl_lds16(bptr[3] + k_, &Bs[b_][boff3]); } } while (0)

#define LOADA(QM) do {                                                         \
  _Pragma("unroll")                                                            \
  for (int mi_ = 0; mi_ < 4; mi_++) {                                          \
    int r_ = wm * 128 + (QM) * 64 + mi_ * 16 + l15;                            \
    _Pragma("unroll")                                                          \
    for (int kk_ = 0; kk_ < 2; kk_++) {                                        \
      int kx_ = (kk_ * 4 + l4) ^ (r_ & 7);                                     \
      af_[mi_][kk_] = *(const bf16x8*)&Ac[(r_ * 8 + kx_) * 8];                 \
    }                                                                          \
  } } while (0)

#define LOADB(DST, QN) do {                                                    \
  _Pragma("unroll")                                                            \
  for (int ni_ = 0; ni_ < 2; ni_++) {                                          \
    int r_ = wn * 64 + (QN) * 32 + ni_ * 16 + l15;                             \
    _Pragma("unroll")                                                          \
    for (int kk_ = 0; kk_ < 2; kk_++) {                                        \
      int kx_ = (kk_ * 4 + l4) ^ (r_ & 7);                                     \
      DST[ni_][kk_] = *(const bf16x8*)&Bc[(r_ * 8 + kx_) * 8];                 \
    }                                                                          \
  } } while (0)

#define MMA(QM, QN, BF) do {                                                   \
  __builtin_amdgcn_s_setprio(1);                                               \
  _Pragma("unroll")                                                            \
  for (int kk_ = 0; kk_ < 2; kk_++)                                            \
    _Pragma("unroll")                                                          \
    for (int mi_ = 0; mi_ < 4; mi_++)                                          \
      _Pragma("unroll")                                                        \
      for (int ni_ = 0; ni_ < 2; ni_++)                                        \
        acc[(QM) * 4 + mi_][(QN) * 2 + ni_] =                                  \
            __builtin_amdgcn_mfma_f32_16x16x32_bf16(                           \
                af_[mi_][kk_], BF[ni_][kk_],                                   \
                acc[(QM) * 4 + mi_][(QN) * 2 + ni_], 0, 0, 0);                 \
  __builtin_amdgcn_s_setprio(0);                                               \
} while (0)

#define KTILE(t, NTT, WAIT1, WAIT4) do {                                       \
  const __bf16* Ac = &As[(t) & 1][0];                                          \
  const __bf16* Bc = &Bs[(t) & 1][0];                                          \
  bf16x8 af_[4][2], bf0_[2][2], bf1_[2][2];                                    \
  /* p1 (0,0) */                                                               \
  LOADA(0); LOADB(bf0_, 0); STAGE_A1((t) + 1, NTT);                            \
  BARRIER(); MMA(0, 0, bf0_); WAIT1; BARRIER();                                \
  /* p2 (0,1) */                                                               \
  LOADB(bf1_, 1); STAGE_B1((t) + 1, NTT);                                      \
  BARRIER(); MMA(0, 1, bf1_); BARRIER();                                       \
  /* p3 (1,1) */                                                               \
  LOADA(1); STAGE_A0((t) + 2, NTT);                                            \
  BARRIER(); MMA(1, 1, bf1_); BARRIER();                                       \
  /* p4 (1,0) — no ds_reads, bf0_ held since p1 */                             \
  STAGE_B0((t) + 2, NTT);                                                      \
  BARRIER(); MMA(1, 0, bf0_); WAIT4; BARRIER();                                \
} while (0)

// ---------------- GEMM1: gathered x @ BguT[e], fused SwiGLU, scaled by we ---
__global__ __launch_bounds__(512, 2) void gemm1_kernel(
    const __bf16* __restrict__ xb, const __bf16* __restrict__ BguT,
    const int* __restrict__ rowtok, const float* __restrict__ rowwt,
    const int* __restrict__ cnt, const int* __restrict__ tileoff,
    __bf16* __restrict__ hid)
{
  __shared__ __bf16 As[2][256 * 64];
  __shared__ __bf16 Bs[2][256 * 64];
  __shared__ int   s_tok[256];
  __shared__ float s_wt[256];

  int y = blockIdx.y;
  if (y >= tileoff[8]) return;
  int e = 0;
  while (y >= tileoff[e + 1]) e++;
  int m0 = (y - tileoff[e]) << 8;
  int cntE = cnt[e];
  int tid = threadIdx.x;
  if (tid < 256) {
    int m = m0 + tid;
    bool v = m < cntE;
    s_tok[tid] = v ? rowtok[e * T_TOK + m] : 0;
    s_wt [tid] = v ? rowwt [e * T_TOK + m] : 0.f;
  }
  __syncthreads();

  const int n0 = blockIdx.x << 8;
  const __bf16* Bp = BguT + (size_t)e * NGU * D_DIM;
  const int lane = tid & 63;
  const int wid  = tid >> 6;
  const int wm = wid >> 2, wn = wid & 3;     // 2(M) x 4(N) waves, 128x64 each
  const int l15 = lane & 15, l4 = lane >> 4;

  // per-thread staging geometry: rr = LDS row-in-call, ch = k-chunk
  const int rr = tid >> 3, ch = tid & 7;
  const int swz = (ch ^ (rr & 7)) << 3;       // row&7 == rr&7 for all calls
  const int rB = rr + ((rr >> 5) << 5);       // rr<32 ? rr : rr+32
  const int aoff = rr * 64 + ch * 8;          // quarter-0 LDS elem offset

  const __bf16* aptr[4];
#pragma unroll
  for (int Q = 0; Q < 4; Q++)
    aptr[Q] = xb + (size_t)(s_tok[Q * 64 + rr] >> 1) * D_DIM + swz;
  const __bf16* bptr[4];
  const int bb0 = 0, bb1 = 32, bb2 = 128, bb3 = 160;
  bptr[0] = Bp + (size_t)(n0 + bb0 + rB) * D_DIM + swz;
  bptr[1] = Bp + (size_t)(n0 + bb1 + rB) * D_DIM + swz;
  bptr[2] = Bp + (size_t)(n0 + bb2 + rB) * D_DIM + swz;
  bptr[3] = Bp + (size_t)(n0 + bb3 + rB) * D_DIM + swz;
  const int boff0 = (bb0 + rB) * 64 + ch * 8;
  const int boff1 = (bb1 + rB) * 64 + ch * 8;
  const int boff2 = (bb2 + rB) * 64 + ch * 8;
  const int boff3 = (bb3 + rB) * 64 + ch * 8;

  f32x4 acc[8][4];
#pragma unroll
  for (int a = 0; a < 8; a++)
#pragma unroll
    for (int b = 0; b < 4; b++) acc[a][b] = (f32x4){0.f, 0.f, 0.f, 0.f};

  // prologue: tile0 full + tile1 A0,B0; vmcnt(8) -> tile0 A0,B0 landed
  STAGE_A0(0, 16); STAGE_B0(0, 16); STAGE_A1(0, 16); STAGE_B1(0, 16);
  STAGE_A0(1, 16); STAGE_B0(1, 16);
  VM8;
  BARRIER();

  for (int t = 0; t < 15; t++) KTILE(t, 16, VM6, VM8);
  // peeled last tile: pre-drain A0/B0(15); VM0 after p1 lands A1/B1(15)
  VM4;
  BARRIER();
  KTILE(15, 16, VM0, VM_NONE);

  // SwiGLU epilogue: n-tile pair (even=gate, odd=up) is lane-aligned
#pragma unroll
  for (int mi = 0; mi < 8; mi++) {
#pragma unroll
    for (int p2 = 0; p2 < 2; p2++) {
      f32x4 gt = acc[mi][2 * p2];
      f32x4 up = acc[mi][2 * p2 + 1];
      int nb = n0 + wn * 64 + p2 * 32;
      int h = ((nb >> 5) << 4) + l15;
#pragma unroll
      for (int r = 0; r < 4; r++) {
        int rl = wm * 128 + mi * 16 + l4 * 4 + r;
        if (m0 + rl < cntE) {
          float u = up[r];
          float hv = (u / (1.f + __expf(-u))) * gt[r] * s_wt[rl];
          hid[(size_t)s_tok[rl] * H_DIM + h] = (__bf16)hv;
        }
      }
    }
  }
}

// ---------------- GEMM2: hid @ BdT[e], K-split x2, store ytmp[z][2T][D] -----
__global__ __launch_bounds__(512, 2) void gemm2_kernel(
    const __bf16* __restrict__ hid, const __bf16* __restrict__ BdT,
    const int* __restrict__ rowtok, const int* __restrict__ cnt,
    const int* __restrict__ tileoff, float* __restrict__ ytmp)
{
  __shared__ __bf16 As[2][256 * 64];
  __shared__ __bf16 Bs[2][256 * 64];
  __shared__ int s_tok[256];

  int y = blockIdx.y;
  if (y >= tileoff[8]) return;
  int e = 0;
  while (y >= tileoff[e + 1]) e++;
  int m0 = (y - tileoff[e]) << 8;
  int cntE = cnt[e];
  int tid = threadIdx.x;
  if (tid < 256) {
    int m = m0 + tid;
    s_tok[tid] = (m < cntE) ? rowtok[e * T_TOK + m] : 0;
  }
  __syncthreads();

  const int n0 = blockIdx.x << 8;            // 4 n-blocks over D=1024
  const int kz = blockIdx.z << 11;           // K-half offset (0 / 2048)
  const __bf16* Bp = BdT + (size_t)e * D_DIM * H_DIM;
  const int lane = tid & 63;
  const int wid  = tid >> 6;
  const int wm = wid >> 2, wn = wid & 3;
  const int l15 = lane & 15, l4 = lane >> 4;

  const int rr = tid >> 3, ch = tid & 7;
  const int swz = (ch ^ (rr & 7)) << 3;
  const int rB = rr + ((rr >> 5) << 5);
  const int aoff = rr * 64 + ch * 8;

  const __bf16* aptr[4];
#pragma unroll
  for (int Q = 0; Q < 4; Q++)
    aptr[Q] = hid + (size_t)s_tok[Q * 64 + rr] * H_DIM + kz + swz;
  const __bf16* bptr[4];
  const int bb0 = 0, bb1 = 32, bb2 = 128, bb3 = 160;
  bptr[0] = Bp + (size_t)(n0 + bb0 + rB) * H_DIM + kz + swz;
  bptr[1] = Bp + (size_t)(n0 + bb1 + rB) * H_DIM + kz + swz;
  bptr[2] = Bp + (size_t)(n0 + bb2 + rB) * H_DIM + kz + swz;
  bptr[3] = Bp + (size_t)(n0 + bb3 + rB) * H_DIM + kz + swz;
  const int boff0 = (bb0 + rB) * 64 + ch * 8;
  const int boff1 = (bb1 + rB) * 64 + ch * 8;
  const int boff2 = (bb2 + rB) * 64 + ch * 8;
  const int boff3 = (bb3 + rB) * 64 + ch * 8;

  f32x4 acc[8][4];
#pragma unroll
  for (int a = 0; a < 8; a++)
#pragma unroll
    for (int b = 0; b < 4; b++) acc[a][b] = (f32x4){0.f, 0.f, 0.f, 0.f};

  STAGE_A0(0, 32); STAGE_B0(0, 32); STAGE_A1(0, 32); STAGE_B1(0, 32);
  STAGE_A0(1, 32); STAGE_B0(1, 32);
  VM8;
  BARRIER();

  for (int t = 0; t < 31; t++) KTILE(t, 32, VM6, VM8);
  VM4;
  BARRIER();
  KTILE(31, 32, VM0, VM_NONE);

  float* yz = ytmp + (size_t)blockIdx.z * (2 * T_TOK) * D_DIM;
#pragma unroll
  for (int mi = 0; mi < 8; mi++)
#pragma unroll
    for (int nj = 0; nj < 4; nj++) {
      int coln = n0 + wn * 64 + nj * 16 + l15;
#pragma unroll
      for (int r = 0; r < 4; r++) {
        int rl = wm * 128 + mi * 16 + l4 * 4 + r;
        if (m0 + rl < cntE)
          yz[(size_t)s_tok[rl] * D_DIM + coln] = acc[mi][nj][r];
      }
    }
}

// ---------------- combine: out[t] = sum of 2 slots x 2 K-halves -------------
__global__ __launch_bounds__(256) void combine_kernel(
    const float* __restrict__ ytmp, float* __restrict__ out)
{
  size_t i = ((size_t)blockIdx.x * 256 + threadIdx.x) * 4;
  size_t t = i >> 10;            // D=1024
  size_t col = i & 1023;
  const size_t HZ = (size_t)(2 * T_TOK) * D_DIM;
  const float4 a = *(const float4*)(ytmp + ((t * 2) << 10) + col);
  const float4 b = *(const float4*)(ytmp + ((t * 2 + 1) << 10) + col);
  const float4 c = *(const float4*)(ytmp + HZ + ((t * 2) << 10) + col);
  const float4 d = *(const float4*)(ytmp + HZ + ((t * 2 + 1) << 10) + col);
  float4 o = {a.x + b.x + c.x + d.x, a.y + b.y + c.y + d.y,
              a.z + b.z + c.z + d.z, a.w + b.w + c.w + d.w};
  *(float4*)(out + i) = o;
}

// ---------------- launch ----------------------------------------------------
extern "C" void kernel_launch(void* const* d_in, const int* in_sizes, int n_in,
                              void* d_out, int out_size, void* d_ws, size_t ws_size,
                              hipStream_t stream)
{
  const float* x    = (const float*)d_in[0];
  const float* rw   = (const float*)d_in[1];
  const float* temp = (const float*)d_in[2];
  const float* Wg   = (const float*)d_in[3];
  const float* Wu   = (const float*)d_in[4];
  const float* Wd   = (const float*)d_in[5];
  float* out = (float*)d_out;

  char* ws = (char*)d_ws;
  size_t off = 0;
  auto alloc = [&](size_t bytes) -> void* {
    void* p = ws + off;
    off = (off + bytes + 255) & ~(size_t)255;
    return p;
  };
  __bf16* xb     = (__bf16*)alloc((size_t)T_TOK * D_DIM * 2);
  __bf16* BguT   = (__bf16*)alloc((size_t)NEXP * NGU * D_DIM * 2);
  __bf16* BdT    = (__bf16*)alloc((size_t)NEXP * D_DIM * H_DIM * 2);
  __bf16* hid    = (__bf16*)alloc((size_t)T_TOK * 2 * H_DIM * 2);
  int*    rowtok = (int*)  alloc((size_t)NEXP * T_TOK * 4);
  float*  rowwt  = (float*)alloc((size_t)NEXP * T_TOK * 4);
  int*    cnt    = (int*)  alloc(64);
  int*    tileoff= (int*)  alloc(64);
  float*  imp_part = (float*)alloc(2048 * 8 * 4);
  float*  ent_part = (float*)alloc(2048 * 4);
  // ytmp (2 K-halves x 2T x D fp32 = 128 MiB) aliases BguT (128 MiB): BguT is
  // dead after gemm1; gemm2 (stream-ordered) writes ytmp, combine reads it.
  float* ytmp = (float*)BguT;
  (void)ws_size; (void)n_in; (void)in_sizes;

  hipMemsetAsync(cnt, 0, 64, stream);

  router_kernel<<<2048, 256, 0, stream>>>(x, rw, temp, xb, rowtok, rowwt, cnt,
                                          imp_part, ent_part);
  aux_final_kernel<<<1, 256, 0, stream>>>(imp_part, ent_part, cnt, tileoff,
                                          out + (size_t)T_TOK * D_DIM);
  transpose_all_kernel<<<dim3(512, 1, 24), 256, 0, stream>>>(Wg, Wu, Wd,
                                                             BguT, BdT);
  gemm1_kernel<<<dim3(32, MAX_YT), 512, 0, stream>>>(xb, BguT, rowtok, rowwt,
                                                     cnt, tileoff, hid);
  gemm2_kernel<<<dim3(4, MAX_YT, 2), 512, 0, stream>>>(hid, BdT, rowtok, cnt,
                                                       tileoff, ytmp);
  combine_kernel<<<8192, 256, 0, stream>>>(ytmp, out);
}

// Round 4
// 1199.456 us; speedup vs baseline: 1.1256x; 1.0319x over previous
//
#include <hip/hip_runtime.h>
#include <stdint.h>

#define T_TOK 8192
#define D_DIM 1024
#define H_DIM 4096
#define NGU   8192          // 2*H interleaved gate/up columns
#define NEXP  8
#define MAX_YT 72           // sum ceil(cnt_e/256) <= 2*8192/256 + 8

typedef float  f32x4  __attribute__((ext_vector_type(4)));
typedef __bf16 bf16x8 __attribute__((ext_vector_type(8)));
typedef __bf16 bf16x4 __attribute__((ext_vector_type(4)));

__device__ __forceinline__ void gl_lds16(const void* g, void* l) {
  // async global->LDS, 16B/lane; LDS dest = wave-uniform base + lane*16
  __builtin_amdgcn_global_load_lds(
      (__attribute__((address_space(1))) void*)g,
      (__attribute__((address_space(3))) void*)l, 16u, 0, 0u);
}

// compile-time fence + runtime barrier: sched_barrier(0) keeps the compiler
// from moving ds_reads across the cross-wave vmcnt landing guarantee.
#define SFENCE() __builtin_amdgcn_sched_barrier(0)
#define BARRIER() do { SFENCE(); __builtin_amdgcn_s_barrier(); SFENCE(); } while (0)
#define VM0 asm volatile("s_waitcnt vmcnt(0)" ::: "memory")
#define VM4 asm volatile("s_waitcnt vmcnt(4)" ::: "memory")
#define VM6 asm volatile("s_waitcnt vmcnt(6)" ::: "memory")
#define VM8 asm volatile("s_waitcnt vmcnt(8)" ::: "memory")
#define VM_NONE ((void)0)

// ---------------- router (+ fused x->bf16 cast) -----------------------------
__global__ __launch_bounds__(256) void router_kernel(
    const float* __restrict__ x, const float* __restrict__ rw,
    const float* __restrict__ temp, __bf16* __restrict__ xb,
    int* __restrict__ rowtok, float* __restrict__ rowwt,
    int* __restrict__ cnt, float* __restrict__ imp_part,
    float* __restrict__ ent_part)
{
  const int wid  = threadIdx.x >> 6;
  const int lane = threadIdx.x & 63;
  const int t    = blockIdx.x * 4 + wid;   // one wave per token

  float acc[8];
#pragma unroll
  for (int e = 0; e < 8; e++) acc[e] = 0.f;
  const float* xr = x + (size_t)t * D_DIM;
#pragma unroll
  for (int it = 0; it < 4; it++) {
    int d = (it * 64 + lane) * 4;
    float4 v = *(const float4*)(xr + d);
    bf16x4 o;
    o[0] = (__bf16)v.x; o[1] = (__bf16)v.y;
    o[2] = (__bf16)v.z; o[3] = (__bf16)v.w;
    *(bf16x4*)(xb + (size_t)t * D_DIM + d) = o;
    float vv[4] = {v.x, v.y, v.z, v.w};
#pragma unroll
    for (int j = 0; j < 4; j++) {
      float xv = vv[j];
      const float4 r0 = *(const float4*)(rw + (d + j) * 8);
      const float4 r1 = *(const float4*)(rw + (d + j) * 8 + 4);
      acc[0] += xv * r0.x; acc[1] += xv * r0.y;
      acc[2] += xv * r0.z; acc[3] += xv * r0.w;
      acc[4] += xv * r1.x; acc[5] += xv * r1.y;
      acc[6] += xv * r1.z; acc[7] += xv * r1.w;
    }
  }
#pragma unroll
  for (int e = 0; e < 8; e++) {
    float v = acc[e];
#pragma unroll
    for (int off = 32; off > 0; off >>= 1) v += __shfl_xor(v, off, 64);
    acc[e] = v;     // all lanes now hold the full logit
  }
  float tclamp = fminf(fmaxf(temp[0], 0.1f), 5.0f);
  float invt = 1.0f / tclamp;
  float mx = -1e30f;
#pragma unroll
  for (int e = 0; e < 8; e++) { acc[e] *= invt; mx = fmaxf(mx, acc[e]); }
  float p[8]; float s = 0.f;
#pragma unroll
  for (int e = 0; e < 8; e++) { p[e] = __expf(acc[e] - mx); s += p[e]; }
  float invs = 1.0f / s;
  float ent = 0.f;
#pragma unroll
  for (int e = 0; e < 8; e++) {
    p[e] *= invs;
    ent -= p[e] * __logf(fmaxf(p[e], 1e-8f));
  }
  // top-2, ties -> lowest index (matches jax top_k)
  int i1 = 0; float w1 = p[0];
#pragma unroll
  for (int e = 1; e < 8; e++) if (p[e] > w1) { w1 = p[e]; i1 = e; }
  int i2 = (i1 == 0) ? 1 : 0; float w2 = p[i2];
#pragma unroll
  for (int e = 0; e < 8; e++) if (e != i1 && p[e] > w2) { w2 = p[e]; i2 = e; }

  __shared__ float s_imp[4][8];
  __shared__ float s_ent[4];
  if (lane == 0) {
    int pos1 = atomicAdd(&cnt[i1], 1);
    rowtok[i1 * T_TOK + pos1] = t * 2;        // hid row index = t*2 + slot
    rowwt [i1 * T_TOK + pos1] = w1;
    int pos2 = atomicAdd(&cnt[i2], 1);
    rowtok[i2 * T_TOK + pos2] = t * 2 + 1;
    rowwt [i2 * T_TOK + pos2] = w2;
#pragma unroll
    for (int e = 0; e < 8; e++) s_imp[wid][e] = p[e];
    s_ent[wid] = ent;
  }
  __syncthreads();
  if (threadIdx.x < 8) {
    int e = threadIdx.x;
    imp_part[blockIdx.x * 8 + e] =
        s_imp[0][e] + s_imp[1][e] + s_imp[2][e] + s_imp[3][e];
  } else if (threadIdx.x == 8) {
    ent_part[blockIdx.x] = s_ent[0] + s_ent[1] + s_ent[2] + s_ent[3];
  }
}

// ---------------- aux losses + GEMM tile schedule (256-row M tiles) ---------
__global__ __launch_bounds__(256) void aux_final_kernel(
    const float* __restrict__ imp_part, const float* __restrict__ ent_part,
    const int* __restrict__ cnt, int* __restrict__ tileoff,
    float* __restrict__ out_aux)
{
  __shared__ float simp[256];
  __shared__ float sent[256];
  int tid = threadIdx.x;
  int e = tid & 7, g = tid >> 3;
  float ia = 0.f;
  for (int b = g; b < 2048; b += 32) ia += imp_part[b * 8 + e];
  simp[tid] = ia;
  float ea = 0.f;
  for (int b = tid; b < 2048; b += 256) ea += ent_part[b];
  sent[tid] = ea;
  __syncthreads();
  if (tid == 0) {
    float imp[8] = {0,0,0,0,0,0,0,0};
    float ent = 0.f;
    for (int i = 0; i < 256; i++) { imp[i & 7] += simp[i]; ent += sent[i]; }
    float aux = 0.f;
    for (int ee = 0; ee < 8; ee++) {
      float importance = imp[ee] / 8192.0f;
      float load = (float)cnt[ee] / (8192.0f + 1e-6f);
      aux += importance * load;
    }
    out_aux[0] = aux * 8.0f * 0.01f;
    out_aux[1] = (ent / 8192.0f) * 0.01f;
    out_aux[2] = 0.f;
    int off = 0;
    for (int ee = 0; ee < 8; ee++) { tileoff[ee] = off; off += (cnt[ee] + 255) >> 8; }
    tileoff[8] = off;
  }
}

// ---------------- fused vectorized transpose+cast of all weights ------------
__global__ __launch_bounds__(256) void transpose_all_kernel(
    const float* __restrict__ Wg, const float* __restrict__ Wu,
    const float* __restrict__ Wd,
    __bf16* __restrict__ BguT, __bf16* __restrict__ BdT)
{
  __shared__ float tile[64 * 129];
  int z = blockIdx.z;
  const float* src; __bf16* dst;
  int C, Kd, r0, c0, up = 0;
  bool gu = z < 16;
  if (gu) {
    int e = z >> 1; up = z & 1;
    src = (up ? Wu : Wg) + (size_t)e * D_DIM * H_DIM;
    dst = BguT + (size_t)e * NGU * D_DIM;
    C = H_DIM; Kd = D_DIM;
    c0 = (blockIdx.x & 31) << 7;  r0 = (blockIdx.x >> 5) << 6;
  } else {
    int e = z - 16;
    src = Wd + (size_t)e * H_DIM * D_DIM;
    dst = BdT + (size_t)e * D_DIM * H_DIM;
    C = D_DIM; Kd = H_DIM;
    c0 = (blockIdx.x & 7) << 7;   r0 = (blockIdx.x >> 3) << 6;
  }
  int t = threadIdx.x;
  int cq = t & 31, rb = t >> 5;
#pragma unroll
  for (int i = 0; i < 8; i++) {
    int r = rb + 8 * i;
    float4 v = *(const float4*)(src + (size_t)(r0 + r) * C + c0 + cq * 4);
    *(float4*)&tile[r * 129 + cq * 4] = v;
  }
  __syncthreads();
#pragma unroll
  for (int i = 0; i < 4; i++) {
    int c = t + (i << 8);         // chunk id 0..1023
    int hl = c >> 3;              // dst-row local (src-col local) 0..127
    int rc = c & 7;               // 8-elem k-chunk within dst row
    int dstrow;
    if (gu) { int h = c0 + hl; dstrow = ((h >> 4) << 5) + (h & 15) + (up << 4); }
    else    { dstrow = c0 + hl; }
    bf16x8 o;
#pragma unroll
    for (int j = 0; j < 8; j++)
      o[j] = (__bf16)tile[(rc * 8 + j) * 129 + hl];
    *(bf16x8*)(dst + (size_t)dstrow * Kd + r0 + rc * 8) = o;
  }
}

// ---------------- 256x256 drift-scheduled GEMM machinery --------------------
// LDS tile layout (per buffer): row-major [256 rows][64 K], XOR-swizzled:
// LDS chunk c of row r holds global k-chunk (c ^ (r&7)); read with the same
// XOR -> ds_read_b128 conflict-free.
//
// 4 sub-phases, TWO barriers per K-tile (minimal load-bearing set):
//   p1: read A0-frags(8)+B0-frags(4); stage A1(t+1); MMA(0,0); VM6; B1.
//   p2: read B1-frags(4); stage B1(t+1); MMA(0,1)
//   p3: read A1-frags(8); stage A0(t+2); MMA(1,1)
//   p4: stage B0(t+2); MMA(1,0); VM8; B4.
// Waves drift freely across p2-p4 (one wave's MFMA hides another's ds_reads
// and gl_lds latency) — replaces the multi-block overlap a 1-block/CU kernel
// can't have.  Hazard ledger:
//  - A0/B0 regions (cur buf) read only in p1 (pre-B1); overwritten by stages
//    issued p3/p4 (post-B1) -> B1 separates.  B1-region read p2, A1-region
//    read p3; their cur-buf overwrites happen next tile p1/p2, separated by
//    B4.  Stages at p1/p2 target buf t+1 whose last readers finished before
//    B4(t-1).
//  - Landing: VM6+B1 publishes A1(t),B1(t) [issued (t-1).p1/p2] for p2/p3
//    reads; VM8+B4 publishes A0(t+1),B0(t+1) [issued (t-1).p3/p4, a full
//    tile of latency-hiding] for next p1.  vmcnt never 0 in the loop.
//  - TAIL: last tile's feeder stages are guard-skipped so VM8 under-counts
//    -> peel: VM4+barrier pre-drains A0/B0(NT-1); VM0 after its MMA(0,0)
//    lands A1/B1(NT-1) before B1 publishes them.

#define STAGE_A0(tt, NTT) do { if ((tt) < (NTT)) {                             \
    int b_ = (tt) & 1; int k_ = (tt) << 6;                                     \
    gl_lds16(aptr[0] + k_, &As[b_][aoff]);                                     \
    gl_lds16(aptr[2] + k_, &As[b_][aoff + 2 * 4096]); } } while (0)
#define STAGE_A1(tt, NTT) do { if ((tt) < (NTT)) {                             \
    int b_ = (tt) & 1; int k_ = (tt) << 6;                                     \
    gl_lds16(aptr[1] + k_, &As[b_][aoff + 1 * 4096]);                          \
    gl_lds16(aptr[3] + k_, &As[b_][aoff + 3 * 4096]); } } while (0)
#define STAGE_B0(tt, NTT) do { if ((tt) < (NTT)) {                             \
    int b_ = (tt) & 1; int k_ = (tt) << 6;                                     \
    gl_lds16(bptr[0] + k_, &Bs[b_][boff0]);                                    \
    gl_lds16(bptr[2] + k_, &Bs[b_][boff2]); } } while (0)
#define STAGE_B1(tt, NTT) do { if ((tt) < (NTT)) {                             \
    int b_ = (tt) & 1; int k_ = (tt) << 6;                                     \
    gl_lds16(bptr[1] + k_, &Bs[b_][boff1]);                                    \
    gl_lds16(bptr[3] + k_, &Bs[b_][boff3]); } } while (0)

#define LOADA(QM) do {                                                         \
  _Pragma("unroll")                                                            \
  for (int mi_ = 0; mi_ < 4; mi_++) {                                          \
    int r_ = wm * 128 + (QM) * 64 + mi_ * 16 + l15;                            \
    _Pragma("unroll")                                                          \
    for (int kk_ = 0; kk_ < 2; kk_++) {                                        \
      int kx_ = (kk_ * 4 + l4) ^ (r_ & 7);                                     \
      af_[mi_][kk_] = *(const bf16x8*)&Ac[(r_ * 8 + kx_) * 8];                 \
    }                                                                          \
  } } while (0)

#define LOADB(DST, QN) do {                                                    \
  _Pragma("unroll")                                                            \
  for (int ni_ = 0; ni_ < 2; ni_++) {                                          \
    int r_ = wn * 64 + (QN) * 32 + ni_ * 16 + l15;                             \
    _Pragma("unroll")                                                          \
    for (int kk_ = 0; kk_ < 2; kk_++) {                                        \
      int kx_ = (kk_ * 4 + l4) ^ (r_ & 7);                                     \
      DST[ni_][kk_] = *(const bf16x8*)&Bc[(r_ * 8 + kx_) * 8];                 \
    }                                                                          \
  } } while (0)

#define MMA(QM, QN, BF) do {                                                   \
  __builtin_amdgcn_s_setprio(1);                                               \
  _Pragma("unroll")                                                            \
  for (int kk_ = 0; kk_ < 2; kk_++)                                            \
    _Pragma("unroll")                                                          \
    for (int mi_ = 0; mi_ < 4; mi_++)                                          \
      _Pragma("unroll")                                                        \
      for (int ni_ = 0; ni_ < 2; ni_++)                                        \
        acc[(QM) * 4 + mi_][(QN) * 2 + ni_] =                                  \
            __builtin_amdgcn_mfma_f32_16x16x32_bf16(                           \
                af_[mi_][kk_], BF[ni_][kk_],                                   \
                acc[(QM) * 4 + mi_][(QN) * 2 + ni_], 0, 0, 0);                 \
  __builtin_amdgcn_s_setprio(0);                                               \
} while (0)

#define KTILE(t, NTT, WAIT1, WAIT4) do {                                       \
  const __bf16* Ac = &As[(t) & 1][0];                                          \
  const __bf16* Bc = &Bs[(t) & 1][0];                                          \
  bf16x8 af_[4][2], bf0_[2][2], bf1_[2][2];                                    \
  /* p1 */                                                                     \
  LOADA(0); LOADB(bf0_, 0); STAGE_A1((t) + 1, NTT);                            \
  MMA(0, 0, bf0_);                                                             \
  WAIT1; BARRIER();                                                            \
  /* p2 */                                                                     \
  LOADB(bf1_, 1); STAGE_B1((t) + 1, NTT);                                      \
  MMA(0, 1, bf1_);                                                             \
  /* p3 */                                                                     \
  LOADA(1); STAGE_A0((t) + 2, NTT);                                            \
  MMA(1, 1, bf1_);                                                             \
  /* p4 — no ds_reads, bf0_ held since p1 */                                   \
  STAGE_B0((t) + 2, NTT);                                                      \
  MMA(1, 0, bf0_);                                                             \
  WAIT4; BARRIER();                                                            \
} while (0)

// ---------------- GEMM1: gathered x @ BguT[e], fused SwiGLU, scaled by we ---
__global__ __launch_bounds__(512, 2) void gemm1_kernel(
    const __bf16* __restrict__ xb, const __bf16* __restrict__ BguT,
    const int* __restrict__ rowtok, const float* __restrict__ rowwt,
    const int* __restrict__ cnt, const int* __restrict__ tileoff,
    __bf16* __restrict__ hid)
{
  __shared__ __bf16 As[2][256 * 64];
  __shared__ __bf16 Bs[2][256 * 64];
  __shared__ int   s_tok[256];
  __shared__ float s_wt[256];

  int y = blockIdx.y;
  if (y >= tileoff[8]) return;
  int e = 0;
  while (y >= tileoff[e + 1]) e++;
  int m0 = (y - tileoff[e]) << 8;
  int cntE = cnt[e];
  int tid = threadIdx.x;
  if (tid < 256) {
    int m = m0 + tid;
    bool v = m < cntE;
    s_tok[tid] = v ? rowtok[e * T_TOK + m] : 0;
    s_wt [tid] = v ? rowwt [e * T_TOK + m] : 0.f;
  }
  __syncthreads();

  const int n0 = blockIdx.x << 8;
  const __bf16* Bp = BguT + (size_t)e * NGU * D_DIM;
  const int lane = tid & 63;
  const int wid  = tid >> 6;
  const int wm = wid >> 2, wn = wid & 3;     // 2(M) x 4(N) waves, 128x64 each
  const int l15 = lane & 15, l4 = lane >> 4;

  // per-thread staging geometry: rr = LDS row-in-call, ch = k-chunk
  const int rr = tid >> 3, ch = tid & 7;
  const int swz = (ch ^ (rr & 7)) << 3;       // row&7 == rr&7 for all calls
  const int rB = rr + ((rr >> 5) << 5);       // rr<32 ? rr : rr+32
  const int aoff = rr * 64 + ch * 8;          // quarter-0 LDS elem offset

  const __bf16* aptr[4];
#pragma unroll
  for (int Q = 0; Q < 4; Q++)
    aptr[Q] = xb + (size_t)(s_tok[Q * 64 + rr] >> 1) * D_DIM + swz;
  const __bf16* bptr[4];
  const int bb0 = 0, bb1 = 32, bb2 = 128, bb3 = 160;
  bptr[0] = Bp + (size_t)(n0 + bb0 + rB) * D_DIM + swz;
  bptr[1] = Bp + (size_t)(n0 + bb1 + rB) * D_DIM + swz;
  bptr[2] = Bp + (size_t)(n0 + bb2 + rB) * D_DIM + swz;
  bptr[3] = Bp + (size_t)(n0 + bb3 + rB) * D_DIM + swz;
  const int boff0 = (bb0 + rB) * 64 + ch * 8;
  const int boff1 = (bb1 + rB) * 64 + ch * 8;
  const int boff2 = (bb2 + rB) * 64 + ch * 8;
  const int boff3 = (bb3 + rB) * 64 + ch * 8;

  f32x4 acc[8][4];
#pragma unroll
  for (int a = 0; a < 8; a++)
#pragma unroll
    for (int b = 0; b < 4; b++) acc[a][b] = (f32x4){0.f, 0.f, 0.f, 0.f};

  // prologue: tile0 full + tile1 A0,B0; vmcnt(8) -> tile0 A0,B0 landed
  STAGE_A0(0, 16); STAGE_B0(0, 16); STAGE_A1(0, 16); STAGE_B1(0, 16);
  STAGE_A0(1, 16); STAGE_B0(1, 16);
  VM8;
  BARRIER();

  for (int t = 0; t < 15; t++) KTILE(t, 16, VM6, VM8);
  // peeled last tile: pre-drain A0/B0(15); VM0 after p1 lands A1/B1(15)
  VM4;
  BARRIER();
  KTILE(15, 16, VM0, VM_NONE);

  // SwiGLU epilogue: n-tile pair (even=gate, odd=up) is lane-aligned
#pragma unroll
  for (int mi = 0; mi < 8; mi++) {
#pragma unroll
    for (int p2 = 0; p2 < 2; p2++) {
      f32x4 gt = acc[mi][2 * p2];
      f32x4 up = acc[mi][2 * p2 + 1];
      int nb = n0 + wn * 64 + p2 * 32;
      int h = ((nb >> 5) << 4) + l15;
#pragma unroll
      for (int r = 0; r < 4; r++) {
        int rl = wm * 128 + mi * 16 + l4 * 4 + r;
        if (m0 + rl < cntE) {
          float u = up[r];
          float hv = (u / (1.f + __expf(-u))) * gt[r] * s_wt[rl];
          hid[(size_t)s_tok[rl] * H_DIM + h] = (__bf16)hv;
        }
      }
    }
  }
}

// ---------------- GEMM2: hid @ BdT[e], K-split x2, store ytmp[z][2T][D] -----
__global__ __launch_bounds__(512, 2) void gemm2_kernel(
    const __bf16* __restrict__ hid, const __bf16* __restrict__ BdT,
    const int* __restrict__ rowtok, const int* __restrict__ cnt,
    const int* __restrict__ tileoff, float* __restrict__ ytmp)
{
  __shared__ __bf16 As[2][256 * 64];
  __shared__ __bf16 Bs[2][256 * 64];
  __shared__ int s_tok[256];

  int y = blockIdx.y;
  if (y >= tileoff[8]) return;
  int e = 0;
  while (y >= tileoff[e + 1]) e++;
  int m0 = (y - tileoff[e]) << 8;
  int cntE = cnt[e];
  int tid = threadIdx.x;
  if (tid < 256) {
    int m = m0 + tid;
    s_tok[tid] = (m < cntE) ? rowtok[e * T_TOK + m] : 0;
  }
  __syncthreads();

  const int n0 = blockIdx.x << 8;            // 4 n-blocks over D=1024
  const int kz = blockIdx.z << 11;           // K-half offset (0 / 2048)
  const __bf16* Bp = BdT + (size_t)e * D_DIM * H_DIM;
  const int lane = tid & 63;
  const int wid  = tid >> 6;
  const int wm = wid >> 2, wn = wid & 3;
  const int l15 = lane & 15, l4 = lane >> 4;

  const int rr = tid >> 3, ch = tid & 7;
  const int swz = (ch ^ (rr & 7)) << 3;
  const int rB = rr + ((rr >> 5) << 5);
  const int aoff = rr * 64 + ch * 8;

  const __bf16* aptr[4];
#pragma unroll
  for (int Q = 0; Q < 4; Q++)
    aptr[Q] = hid + (size_t)s_tok[Q * 64 + rr] * H_DIM + kz + swz;
  const __bf16* bptr[4];
  const int bb0 = 0, bb1 = 32, bb2 = 128, bb3 = 160;
  bptr[0] = Bp + (size_t)(n0 + bb0 + rB) * H_DIM + kz + swz;
  bptr[1] = Bp + (size_t)(n0 + bb1 + rB) * H_DIM + kz + swz;
  bptr[2] = Bp + (size_t)(n0 + bb2 + rB) * H_DIM + kz + swz;
  bptr[3] = Bp + (size_t)(n0 + bb3 + rB) * H_DIM + kz + swz;
  const int boff0 = (bb0 + rB) * 64 + ch * 8;
  const int boff1 = (bb1 + rB) * 64 + ch * 8;
  const int boff2 = (bb2 + rB) * 64 + ch * 8;
  const int boff3 = (bb3 + rB) * 64 + ch * 8;

  f32x4 acc[8][4];
#pragma unroll
  for (int a = 0; a < 8; a++)
#pragma unroll
    for (int b = 0; b < 4; b++) acc[a][b] = (f32x4){0.f, 0.f, 0.f, 0.f};

  STAGE_A0(0, 32); STAGE_B0(0, 32); STAGE_A1(0, 32); STAGE_B1(0, 32);
  STAGE_A0(1, 32); STAGE_B0(1, 32);
  VM8;
  BARRIER();

  for (int t = 0; t < 31; t++) KTILE(t, 32, VM6, VM8);
  VM4;
  BARRIER();
  KTILE(31, 32, VM0, VM_NONE);

  float* yz = ytmp + (size_t)blockIdx.z * (2 * T_TOK) * D_DIM;
#pragma unroll
  for (int mi = 0; mi < 8; mi++)
#pragma unroll
    for (int nj = 0; nj < 4; nj++) {
      int coln = n0 + wn * 64 + nj * 16 + l15;
#pragma unroll
      for (int r = 0; r < 4; r++) {
        int rl = wm * 128 + mi * 16 + l4 * 4 + r;
        if (m0 + rl < cntE)
          yz[(size_t)s_tok[rl] * D_DIM + coln] = acc[mi][nj][r];
      }
    }
}

// ---------------- combine: out[t] = sum of 2 slots x 2 K-halves -------------
__global__ __launch_bounds__(256) void combine_kernel(
    const float* __restrict__ ytmp, float* __restrict__ out)
{
  size_t i = ((size_t)blockIdx.x * 256 + threadIdx.x) * 4;
  size_t t = i >> 10;            // D=1024
  size_t col = i & 1023;
  const size_t HZ = (size_t)(2 * T_TOK) * D_DIM;
  const float4 a = *(const float4*)(ytmp + ((t * 2) << 10) + col);
  const float4 b = *(const float4*)(ytmp + ((t * 2 + 1) << 10) + col);
  const float4 c = *(const float4*)(ytmp + HZ + ((t * 2) << 10) + col);
  const float4 d = *(const float4*)(ytmp + HZ + ((t * 2 + 1) << 10) + col);
  float4 o = {a.x + b.x + c.x + d.x, a.y + b.y + c.y + d.y,
              a.z + b.z + c.z + d.z, a.w + b.w + c.w + d.w};
  *(float4*)(out + i) = o;
}

// ---------------- launch ----------------------------------------------------
extern "C" void kernel_launch(void* const* d_in, const int* in_sizes, int n_in,
                              void* d_out, int out_size, void* d_ws, size_t ws_size,
                              hipStream_t stream)
{
  const float* x    = (const float*)d_in[0];
  const float* rw   = (const float*)d_in[1];
  const float* temp = (const float*)d_in[2];
  const float* Wg   = (const float*)d_in[3];
  const float* Wu   = (const float*)d_in[4];
  const float* Wd   = (const float*)d_in[5];
  float* out = (float*)d_out;

  char* ws = (char*)d_ws;
  size_t off = 0;
  auto alloc = [&](size_t bytes) -> void* {
    void* p = ws + off;
    off = (off + bytes + 255) & ~(size_t)255;
    return p;
  };
  __bf16* xb     = (__bf16*)alloc((size_t)T_TOK * D_DIM * 2);
  __bf16* BguT   = (__bf16*)alloc((size_t)NEXP * NGU * D_DIM * 2);
  __bf16* BdT    = (__bf16*)alloc((size_t)NEXP * D_DIM * H_DIM * 2);
  __bf16* hid    = (__bf16*)alloc((size_t)T_TOK * 2 * H_DIM * 2);
  int*    rowtok = (int*)  alloc((size_t)NEXP * T_TOK * 4);
  float*  rowwt  = (float*)alloc((size_t)NEXP * T_TOK * 4);
  int*    cnt    = (int*)  alloc(64);
  int*    tileoff= (int*)  alloc(64);
  float*  imp_part = (float*)alloc(2048 * 8 * 4);
  float*  ent_part = (float*)alloc(2048 * 4);
  // ytmp (2 K-halves x 2T x D fp32 = 128 MiB) aliases BguT (128 MiB): BguT is
  // dead after gemm1; gemm2 (stream-ordered) writes ytmp, combine reads it.
  float* ytmp = (float*)BguT;
  (void)ws_size; (void)n_in; (void)in_sizes;

  hipMemsetAsync(cnt, 0, 64, stream);

  router_kernel<<<2048, 256, 0, stream>>>(x, rw, temp, xb, rowtok, rowwt, cnt,
                                          imp_part, ent_part);
  aux_final_kernel<<<1, 256, 0, stream>>>(imp_part, ent_part, cnt, tileoff,
                                          out + (size_t)T_TOK * D_DIM);
  transpose_all_kernel<<<dim3(512, 1, 24), 256, 0, stream>>>(Wg, Wu, Wd,
                                                             BguT, BdT);
  gemm1_kernel<<<dim3(32, MAX_YT), 512, 0, stream>>>(xb, BguT, rowtok, rowwt,
                                                     cnt, tileoff, hid);
  gemm2_kernel<<<dim3(4, MAX_YT, 2), 512, 0, stream>>>(hid, BdT, rowtok, cnt,
                                                       tileoff, ytmp);
  combine_kernel<<<8192, 256, 0, stream>>>(ytmp, out);
}

// Round 5
// 1168.012 us; speedup vs baseline: 1.1559x; 1.0269x over previous
//
#include <hip/hip_runtime.h>
#include <stdint.h>

#define T_TOK 8192
#define D_DIM 1024
#define H_DIM 4096
#define NGU   8192          // 2*H interleaved gate/up columns
#define NEXP  8
#define MAX_YT 136          // 2*T/128 + NEXP worst-case M-tiles

typedef float  f32x4  __attribute__((ext_vector_type(4)));
typedef __bf16 bf16x8 __attribute__((ext_vector_type(8)));
typedef __bf16 bf16x4 __attribute__((ext_vector_type(4)));

__device__ __forceinline__ void gl_lds16(const void* g, void* l) {
  // async global->LDS, 16B/lane; LDS dest = wave-uniform base + lane*16
  __builtin_amdgcn_global_load_lds(
      (__attribute__((address_space(1))) void*)g,
      (__attribute__((address_space(3))) void*)l, 16u, 0, 0u);
}

// ---------------- router (+ fused x->bf16 cast) -----------------------------
__global__ __launch_bounds__(256) void router_kernel(
    const float* __restrict__ x, const float* __restrict__ rw,
    const float* __restrict__ temp, __bf16* __restrict__ xb,
    int* __restrict__ rowtok, float* __restrict__ rowwt,
    int* __restrict__ cnt, float* __restrict__ imp_part,
    float* __restrict__ ent_part)
{
  const int wid  = threadIdx.x >> 6;
  const int lane = threadIdx.x & 63;
  const int t    = blockIdx.x * 4 + wid;   // one wave per token

  float acc[8];
#pragma unroll
  for (int e = 0; e < 8; e++) acc[e] = 0.f;
  const float* xr = x + (size_t)t * D_DIM;
#pragma unroll
  for (int it = 0; it < 4; it++) {
    int d = (it * 64 + lane) * 4;
    float4 v = *(const float4*)(xr + d);
    bf16x4 o;
    o[0] = (__bf16)v.x; o[1] = (__bf16)v.y;
    o[2] = (__bf16)v.z; o[3] = (__bf16)v.w;
    *(bf16x4*)(xb + (size_t)t * D_DIM + d) = o;
    float vv[4] = {v.x, v.y, v.z, v.w};
#pragma unroll
    for (int j = 0; j < 4; j++) {
      float xv = vv[j];
      const float4 r0 = *(const float4*)(rw + (d + j) * 8);
      const float4 r1 = *(const float4*)(rw + (d + j) * 8 + 4);
      acc[0] += xv * r0.x; acc[1] += xv * r0.y;
      acc[2] += xv * r0.z; acc[3] += xv * r0.w;
      acc[4] += xv * r1.x; acc[5] += xv * r1.y;
      acc[6] += xv * r1.z; acc[7] += xv * r1.w;
    }
  }
#pragma unroll
  for (int e = 0; e < 8; e++) {
    float v = acc[e];
#pragma unroll
    for (int off = 32; off > 0; off >>= 1) v += __shfl_xor(v, off, 64);
    acc[e] = v;     // all lanes now hold the full logit
  }
  float tclamp = fminf(fmaxf(temp[0], 0.1f), 5.0f);
  float invt = 1.0f / tclamp;
  float mx = -1e30f;
#pragma unroll
  for (int e = 0; e < 8; e++) { acc[e] *= invt; mx = fmaxf(mx, acc[e]); }
  float p[8]; float s = 0.f;
#pragma unroll
  for (int e = 0; e < 8; e++) { p[e] = __expf(acc[e] - mx); s += p[e]; }
  float invs = 1.0f / s;
  float ent = 0.f;
#pragma unroll
  for (int e = 0; e < 8; e++) {
    p[e] *= invs;
    ent -= p[e] * __logf(fmaxf(p[e], 1e-8f));
  }
  // top-2, ties -> lowest index (matches jax top_k)
  int i1 = 0; float w1 = p[0];
#pragma unroll
  for (int e = 1; e < 8; e++) if (p[e] > w1) { w1 = p[e]; i1 = e; }
  int i2 = (i1 == 0) ? 1 : 0; float w2 = p[i2];
#pragma unroll
  for (int e = 0; e < 8; e++) if (e != i1 && p[e] > w2) { w2 = p[e]; i2 = e; }

  __shared__ float s_imp[4][8];
  __shared__ float s_ent[4];
  if (lane == 0) {
    int pos1 = atomicAdd(&cnt[i1], 1);
    rowtok[i1 * T_TOK + pos1] = t * 2;        // hid row index = t*2 + slot
    rowwt [i1 * T_TOK + pos1] = w1;
    int pos2 = atomicAdd(&cnt[i2], 1);
    rowtok[i2 * T_TOK + pos2] = t * 2 + 1;
    rowwt [i2 * T_TOK + pos2] = w2;
#pragma unroll
    for (int e = 0; e < 8; e++) s_imp[wid][e] = p[e];
    s_ent[wid] = ent;
  }
  __syncthreads();
  if (threadIdx.x < 8) {
    int e = threadIdx.x;
    imp_part[blockIdx.x * 8 + e] =
        s_imp[0][e] + s_imp[1][e] + s_imp[2][e] + s_imp[3][e];
  } else if (threadIdx.x == 8) {
    ent_part[blockIdx.x] = s_ent[0] + s_ent[1] + s_ent[2] + s_ent[3];
  }
}

// ---------------- aux losses + GEMM tile schedule ---------------------------
__global__ __launch_bounds__(256) void aux_final_kernel(
    const float* __restrict__ imp_part, const float* __restrict__ ent_part,
    const int* __restrict__ cnt, int* __restrict__ tileoff,
    float* __restrict__ out_aux)
{
  __shared__ float simp[256];
  __shared__ float sent[256];
  int tid = threadIdx.x;
  int e = tid & 7, g = tid >> 3;
  float ia = 0.f;
  for (int b = g; b < 2048; b += 32) ia += imp_part[b * 8 + e];
  simp[tid] = ia;
  float ea = 0.f;
  for (int b = tid; b < 2048; b += 256) ea += ent_part[b];
  sent[tid] = ea;
  __syncthreads();
  if (tid == 0) {
    float imp[8] = {0,0,0,0,0,0,0,0};
    float ent = 0.f;
    for (int i = 0; i < 256; i++) { imp[i & 7] += simp[i]; ent += sent[i]; }
    float aux = 0.f;
    for (int ee = 0; ee < 8; ee++) {
      float importance = imp[ee] / 8192.0f;
      float load = (float)cnt[ee] / (8192.0f + 1e-6f);
      aux += importance * load;
    }
    out_aux[0] = aux * 8.0f * 0.01f;
    out_aux[1] = (ent / 8192.0f) * 0.01f;
    out_aux[2] = 0.f;
    int off = 0;
    for (int ee = 0; ee < 8; ee++) { tileoff[ee] = off; off += (cnt[ee] + 127) >> 7; }
    tileoff[8] = off;
  }
}

// ---------------- fused vectorized transpose+cast of all weights ------------
__global__ __launch_bounds__(256) void transpose_all_kernel(
    const float* __restrict__ Wg, const float* __restrict__ Wu,
    const float* __restrict__ Wd,
    __bf16* __restrict__ BguT, __bf16* __restrict__ BdT)
{
  __shared__ float tile[64 * 129];
  int z = blockIdx.z;
  const float* src; __bf16* dst;
  int C, Kd, r0, c0, up = 0;
  bool gu = z < 16;
  if (gu) {
    int e = z >> 1; up = z & 1;
    src = (up ? Wu : Wg) + (size_t)e * D_DIM * H_DIM;
    dst = BguT + (size_t)e * NGU * D_DIM;
    C = H_DIM; Kd = D_DIM;
    c0 = (blockIdx.x & 31) << 7;  r0 = (blockIdx.x >> 5) << 6;
  } else {
    int e = z - 16;
    src = Wd + (size_t)e * H_DIM * D_DIM;
    dst = BdT + (size_t)e * D_DIM * H_DIM;
    C = D_DIM; Kd = H_DIM;
    c0 = (blockIdx.x & 7) << 7;   r0 = (blockIdx.x >> 3) << 6;
  }
  int t = threadIdx.x;
  int cq = t & 31, rb = t >> 5;
#pragma unroll
  for (int i = 0; i < 8; i++) {
    int r = rb + 8 * i;
    float4 v = *(const float4*)(src + (size_t)(r0 + r) * C + c0 + cq * 4);
    *(float4*)&tile[r * 129 + cq * 4] = v;
  }
  __syncthreads();
#pragma unroll
  for (int i = 0; i < 4; i++) {
    int c = t + (i << 8);         // chunk id 0..1023
    int hl = c >> 3;              // dst-row local (src-col local) 0..127
    int rc = c & 7;               // 8-elem k-chunk within dst row
    int dstrow;
    if (gu) { int h = c0 + hl; dstrow = ((h >> 4) << 5) + (h & 15) + (up << 4); }
    else    { dstrow = c0 + hl; }
    bf16x8 o;
#pragma unroll
    for (int j = 0; j < 8; j++)
      o[j] = (__bf16)tile[(rc * 8 + j) * 129 + hl];
    *(bf16x8*)(dst + (size_t)dstrow * Kd + r0 + rc * 8) = o;
  }
}

// ---------------- GEMM1: gathered x @ BguT[e], fused SwiGLU, scaled by we ---
// 128x128 tile, BK=64, 16x16x32 bf16 MFMA, XOR-swizzled LDS (conflict-free).
// XCD-bijective block swizzle: consecutive logical x-tiles (sharing an A row
// panel) colocate on one XCD's L2.  grid = 64*136 = 8704, %8 == 0.
__global__ __launch_bounds__(256, 2) void gemm1_kernel(
    const __bf16* __restrict__ xb, const __bf16* __restrict__ BguT,
    const int* __restrict__ rowtok, const float* __restrict__ rowwt,
    const int* __restrict__ cnt, const int* __restrict__ tileoff,
    __bf16* __restrict__ hid)
{
  __shared__ __bf16 As[128 * 64];
  __shared__ __bf16 Bs[128 * 64];
  __shared__ int   s_tok[128];
  __shared__ float s_wt[128];

  const int nblk8 = (64 * MAX_YT) >> 3;
  int hwlin = blockIdx.y * 64 + blockIdx.x;
  int lin = (hwlin & 7) * nblk8 + (hwlin >> 3);
  int y  = lin >> 6;          // gridDim.x == 64
  int bx = lin & 63;

  if (y >= tileoff[8]) return;
  int e = 0;
  while (y >= tileoff[e + 1]) e++;
  int m0 = (y - tileoff[e]) << 7;
  int cntE = cnt[e];
  int tid = threadIdx.x;
  if (tid < 128) {
    int m = m0 + tid;
    bool v = m < cntE;
    s_tok[tid] = v ? rowtok[e * T_TOK + m] : 0;
    s_wt [tid] = v ? rowwt [e * T_TOK + m] : 0.f;
  }
  __syncthreads();

  const int n0 = bx << 7;
  const __bf16* Bp = BguT + (size_t)e * NGU * D_DIM;
  const int lane = tid & 63;
  const int wid = tid >> 6;
  const int wm = wid >> 1, wn = wid & 1;
  const int l15 = lane & 15, l4 = lane >> 4;

  f32x4 zero = {0.f, 0.f, 0.f, 0.f};
  f32x4 acc[4][4];
#pragma unroll
  for (int a = 0; a < 4; a++)
#pragma unroll
    for (int b = 0; b < 4; b++) acc[a][b] = zero;

  int q[4], ar[4], akc[4];
#pragma unroll
  for (int c = 0; c < 4; c++) {
    q[c]   = tid + (c << 8);
    ar[c]  = q[c] >> 3;
    akc[c] = ((q[c] & 7) ^ (ar[c] & 7)) << 3;   // XOR swizzle on global side
  }

  for (int kt = 0; kt < 16; kt++) {
    int k0 = kt << 6;
#pragma unroll
    for (int c = 0; c < 4; c++) {
      const __bf16* ga = xb + (size_t)(s_tok[ar[c]] >> 1) * D_DIM + (k0 + akc[c]);
      gl_lds16(ga, &As[q[c] << 3]);
    }
#pragma unroll
    for (int c = 0; c < 4; c++) {
      const __bf16* gb = Bp + (size_t)(n0 + ar[c]) * D_DIM + (k0 + akc[c]);
      gl_lds16(gb, &Bs[q[c] << 3]);
    }
    __syncthreads();
#pragma unroll
    for (int ks = 0; ks < 2; ks++) {
      bf16x8 af[4], bfv[4];
#pragma unroll
      for (int mi = 0; mi < 4; mi++) {
        int row = wm * 64 + mi * 16 + l15;
        int kidx = (ks * 4 + l4) ^ (row & 7);
        af[mi] = *(const bf16x8*)&As[(row * 8 + kidx) * 8];
      }
#pragma unroll
      for (int ni = 0; ni < 4; ni++) {
        int row = wn * 64 + ni * 16 + l15;
        int kidx = (ks * 4 + l4) ^ (row & 7);
        bfv[ni] = *(const bf16x8*)&Bs[(row * 8 + kidx) * 8];
      }
#pragma unroll
      for (int mi = 0; mi < 4; mi++)
#pragma unroll
        for (int ni = 0; ni < 4; ni++)
          acc[mi][ni] = __builtin_amdgcn_mfma_f32_16x16x32_bf16(
              af[mi], bfv[ni], acc[mi][ni], 0, 0, 0);
    }
    __syncthreads();
  }

  // SwiGLU epilogue: n-tile pair (even=gate, odd=up) is lane-aligned
#pragma unroll
  for (int mi = 0; mi < 4; mi++) {
#pragma unroll
    for (int p2 = 0; p2 < 2; p2++) {
      f32x4 gt = acc[mi][2 * p2];
      f32x4 up = acc[mi][2 * p2 + 1];
      int nb = n0 + wn * 64 + p2 * 32;
      int h = ((nb >> 5) << 4) + l15;
#pragma unroll
      for (int r = 0; r < 4; r++) {
        int rl = wm * 64 + mi * 16 + l4 * 4 + r;
        if (m0 + rl < cntE) {
          float u = up[r];
          float hv = (u / (1.f + __expf(-u))) * gt[r] * s_wt[rl];
          hid[(size_t)s_tok[rl] * H_DIM + h] = (__bf16)hv;
        }
      }
    }
  }
}

// ---------------- GEMM2: hid @ BdT[e], fused combine via atomicAdd ----------
// grid = 8*136 = 1088, %8 == 0.  out pre-zeroed; each (token,slot) block
// atomically accumulates its 128-col strip -> combine kernel eliminated.
__global__ __launch_bounds__(256, 2) void gemm2_kernel(
    const __bf16* __restrict__ hid, const __bf16* __restrict__ BdT,
    const int* __restrict__ rowtok, const int* __restrict__ cnt,
    const int* __restrict__ tileoff, float* __restrict__ out)
{
  __shared__ __bf16 As[128 * 64];
  __shared__ __bf16 Bs[128 * 64];
  __shared__ int s_tok[128];

  const int nblk8 = (8 * MAX_YT) >> 3;
  int hwlin = blockIdx.y * 8 + blockIdx.x;
  int lin = (hwlin & 7) * nblk8 + (hwlin >> 3);
  int y  = lin >> 3;          // gridDim.x == 8
  int bx = lin & 7;

  if (y >= tileoff[8]) return;
  int e = 0;
  while (y >= tileoff[e + 1]) e++;
  int m0 = (y - tileoff[e]) << 7;
  int cntE = cnt[e];
  int tid = threadIdx.x;
  if (tid < 128) {
    int m = m0 + tid;
    s_tok[tid] = (m < cntE) ? rowtok[e * T_TOK + m] : 0;
  }
  __syncthreads();

  const int n0 = bx << 7;
  const __bf16* Bp = BdT + (size_t)e * D_DIM * H_DIM;
  const int lane = tid & 63;
  const int wid = tid >> 6;
  const int wm = wid >> 1, wn = wid & 1;
  const int l15 = lane & 15, l4 = lane >> 4;

  f32x4 zero = {0.f, 0.f, 0.f, 0.f};
  f32x4 acc[4][4];
#pragma unroll
  for (int a = 0; a < 4; a++)
#pragma unroll
    for (int b = 0; b < 4; b++) acc[a][b] = zero;

  int q[4], ar[4], akc[4];
#pragma unroll
  for (int c = 0; c < 4; c++) {
    q[c]   = tid + (c << 8);
    ar[c]  = q[c] >> 3;
    akc[c] = ((q[c] & 7) ^ (ar[c] & 7)) << 3;
  }

  for (int kt = 0; kt < 64; kt++) {
    int k0 = kt << 6;
#pragma unroll
    for (int c = 0; c < 4; c++) {
      const __bf16* ga = hid + (size_t)s_tok[ar[c]] * H_DIM + (k0 + akc[c]);
      gl_lds16(ga, &As[q[c] << 3]);
    }
#pragma unroll
    for (int c = 0; c < 4; c++) {
      const __bf16* gb = Bp + (size_t)(n0 + ar[c]) * H_DIM + (k0 + akc[c]);
      gl_lds16(gb, &Bs[q[c] << 3]);
    }
    __syncthreads();
#pragma unroll
    for (int ks = 0; ks < 2; ks++) {
      bf16x8 af[4], bfv[4];
#pragma unroll
      for (int mi = 0; mi < 4; mi++) {
        int row = wm * 64 + mi * 16 + l15;
        int kidx = (ks * 4 + l4) ^ (row & 7);
        af[mi] = *(const bf16x8*)&As[(row * 8 + kidx) * 8];
      }
#pragma unroll
      for (int ni = 0; ni < 4; ni++) {
        int row = wn * 64 + ni * 16 + l15;
        int kidx = (ks * 4 + l4) ^ (row & 7);
        bfv[ni] = *(const bf16x8*)&Bs[(row * 8 + kidx) * 8];
      }
#pragma unroll
      for (int mi = 0; mi < 4; mi++)
#pragma unroll
        for (int ni = 0; ni < 4; ni++)
          acc[mi][ni] = __builtin_amdgcn_mfma_f32_16x16x32_bf16(
              af[mi], bfv[ni], acc[mi][ni], 0, 0, 0);
    }
    __syncthreads();
  }

#pragma unroll
  for (int mi = 0; mi < 4; mi++)
#pragma unroll
    for (int ni = 0; ni < 4; ni++) {
      int coln = n0 + wn * 64 + ni * 16 + l15;
#pragma unroll
      for (int r = 0; r < 4; r++) {
        int rl = wm * 64 + mi * 16 + l4 * 4 + r;
        if (m0 + rl < cntE)
          atomicAdd(&out[(size_t)(s_tok[rl] >> 1) * D_DIM + coln],
                    acc[mi][ni][r]);
      }
    }
}

// ---------------- launch ----------------------------------------------------
extern "C" void kernel_launch(void* const* d_in, const int* in_sizes, int n_in,
                              void* d_out, int out_size, void* d_ws, size_t ws_size,
                              hipStream_t stream)
{
  const float* x    = (const float*)d_in[0];
  const float* rw   = (const float*)d_in[1];
  const float* temp = (const float*)d_in[2];
  const float* Wg   = (const float*)d_in[3];
  const float* Wu   = (const float*)d_in[4];
  const float* Wd   = (const float*)d_in[5];
  float* out = (float*)d_out;

  char* ws = (char*)d_ws;
  size_t off = 0;
  auto alloc = [&](size_t bytes) -> void* {
    void* p = ws + off;
    off = (off + bytes + 255) & ~(size_t)255;
    return p;
  };
  __bf16* xb     = (__bf16*)alloc((size_t)T_TOK * D_DIM * 2);
  __bf16* BguT   = (__bf16*)alloc((size_t)NEXP * NGU * D_DIM * 2);
  __bf16* BdT    = (__bf16*)alloc((size_t)NEXP * D_DIM * H_DIM * 2);
  __bf16* hid    = (__bf16*)alloc((size_t)T_TOK * 2 * H_DIM * 2);
  int*    rowtok = (int*)  alloc((size_t)NEXP * T_TOK * 4);
  float*  rowwt  = (float*)alloc((size_t)NEXP * T_TOK * 4);
  int*    cnt    = (int*)  alloc(64);
  int*    tileoff= (int*)  alloc(64);
  float*  imp_part = (float*)alloc(2048 * 8 * 4);
  float*  ent_part = (float*)alloc(2048 * 4);
  (void)ws_size; (void)n_in; (void)in_sizes;

  hipMemsetAsync(cnt, 0, 64, stream);
  // zero the gemm-output region (gemm2 accumulates atomically into it);
  // aux slots live at out + T_TOK*D_DIM, untouched by this memset.
  hipMemsetAsync(out, 0, (size_t)T_TOK * D_DIM * sizeof(float), stream);

  router_kernel<<<2048, 256, 0, stream>>>(x, rw, temp, xb, rowtok, rowwt, cnt,
                                          imp_part, ent_part);
  aux_final_kernel<<<1, 256, 0, stream>>>(imp_part, ent_part, cnt, tileoff,
                                          out + (size_t)T_TOK * D_DIM);
  transpose_all_kernel<<<dim3(512, 1, 24), 256, 0, stream>>>(Wg, Wu, Wd,
                                                             BguT, BdT);
  gemm1_kernel<<<dim3(64, MAX_YT), 256, 0, stream>>>(xb, BguT, rowtok, rowwt,
                                                     cnt, tileoff, hid);
  gemm2_kernel<<<dim3(8, MAX_YT), 256, 0, stream>>>(hid, BdT, rowtok, cnt,
                                                    tileoff, out);
}